// Round 3
// baseline (17448.218 us; speedup 1.0000x reference)
//
#include <hip/hip_runtime.h>
#include <hip/hip_bf16.h>
#include <hip/hip_cooperative_groups.h>

namespace cg = cooperative_groups;

// Problem dims
#define S_LEN 128
#define M_B   256
#define E_DIM 1024
#define H_DIM 512
#define G4    2048          // 4*H
#define N_ROWS (S_LEN*M_B)  // 32768
#define KD    1024          // GEMM K for both layers (E = 2H = 1024)

typedef __bf16 bf16_t;
typedef __bf16 bf16x8 __attribute__((ext_vector_type(8)));
typedef float  f32x4  __attribute__((ext_vector_type(4)));

#define AS1(p) ((const __attribute__((address_space(1))) void*)(p))
#define AS3(p) ((__attribute__((address_space(3))) void*)(p))

__device__ __forceinline__ float sigm(float x)     { return 1.f / (1.f + __expf(-x)); }
__device__ __forceinline__ float tanhfast(float x) { return 2.f / (1.f + __expf(-2.f * x)) - 1.f; }

// ---------------------------------------------------------------------------
// Weight permutation + bf16 conversion.
// Gate permutation: j' = q*64 + gate*16 + u16  <->  j = gate*512 + (q*16+u16)
// so one 64-col group holds all 4 gates of 16 units; gate = n-frag index,
// unit = lane&15 (all 4 gates of a unit land in the same lane).
// ---------------------------------------------------------------------------
__global__ __launch_bounds__(256)
void permute_weights_kernel(const float* __restrict__ Wih, const float* __restrict__ Whh,
                            const float* __restrict__ b,
                            bf16_t* __restrict__ Wihp, bf16_t* __restrict__ Whhp,
                            float* __restrict__ bp)
{
    int bid = blockIdx.x;            // d*2048 + jp
    int d  = bid >> 11;
    int jp = bid & 2047;
    int q = jp >> 6, r = jp & 63;
    int gate = r >> 4, u16 = r & 15;
    int j = gate * H_DIM + q * 16 + u16;

    const float* s_ih = Wih + ((size_t)d * G4 + j) * E_DIM;
    bf16_t*      d_ih = Wihp + ((size_t)d * G4 + jp) * E_DIM;
    for (int e = threadIdx.x; e < E_DIM; e += 256) d_ih[e] = (bf16_t)s_ih[e];

    const float* s_hh = Whh + ((size_t)d * G4 + j) * H_DIM;
    bf16_t*      d_hh = Whhp + ((size_t)d * G4 + jp) * H_DIM;
    for (int k = threadIdx.x; k < H_DIM; k += 256) d_hh[k] = (bf16_t)s_hh[k];

    if (threadIdx.x == 0) bp[d * G4 + jp] = b[d * G4 + j];
}

// ---------------------------------------------------------------------------
// Embedding lookup -> bf16 X (32768 x 1024). emb[PAD_ID] is zero.
// ---------------------------------------------------------------------------
__global__ __launch_bounds__(256)
void embed_kernel(const int* __restrict__ F, const float* __restrict__ emb,
                  bf16_t* __restrict__ X)
{
    int n   = blockIdx.x;            // t*256 + m
    int tok = F[n];
    const float4* src = (const float4*)(emb + (size_t)tok * E_DIM);
    bf16_t*       dst = X + (size_t)n * E_DIM;
    for (int i = threadIdx.x; i < E_DIM / 4; i += 256) {
        float4 v = src[i];
        dst[i * 4 + 0] = (bf16_t)v.x;
        dst[i * 4 + 1] = (bf16_t)v.y;
        dst[i * 4 + 2] = (bf16_t)v.z;
        dst[i * 4 + 3] = (bf16_t)v.w;
    }
}

// ---------------------------------------------------------------------------
// srcrow[t*256+m] = ((t < L) ? L-1-t : t) * 256 + m   (self-inverse gather)
// ---------------------------------------------------------------------------
__global__ __launch_bounds__(256)
void rowmap_kernel(const int* __restrict__ F_lens, int* __restrict__ srcrow)
{
    int n = blockIdx.x * 256 + threadIdx.x;
    int t = n >> 8, m = n & 255;
    int L = F_lens[m];
    int st = (t < L) ? (L - 1 - t) : t;
    srcrow[n] = st * M_B + m;
}

// ---------------------------------------------------------------------------
// Chunked input-projection GEMM:
//   PREc[d][r][j'] = A[gather(rowbase+r)][:] . Wp[d][j'][:] + bp[d][j']
// d=0: natural rows; d=1: rows gathered via srcrow (pre-reversed input).
// 128x128 tile, BK=32, 4 waves 2x2, 16x16x32 bf16 MFMA, f32 out.
// ---------------------------------------------------------------------------
#define BM 128
#define BN 128
#define BK 32

__global__ __launch_bounds__(256)
void gemm_pre_kernel(const bf16_t* __restrict__ A,    // (32768, 1024) bf16
                     const bf16_t* __restrict__ Wp,   // (2, 2048, 1024) bf16
                     const float* __restrict__ bp,    // (2, 2048)
                     const int* __restrict__ srcrow,  // (32768)
                     float* __restrict__ PREc,        // (2, TCR, 2048)
                     int rowbase, int TCR)
{
    const int d    = blockIdx.z;
    const int n0   = blockIdx.x * BN;
    const int mloc = blockIdx.y * BM;
    const int tid  = threadIdx.x;
    const int lane = tid & 63, wave = tid >> 6;
    const int wm = wave >> 1, wn = wave & 1;
    const int fr = lane & 15, fq = lane >> 4;

    __shared__ __attribute__((aligned(16))) bf16_t At[BM * BK];
    __shared__ __attribute__((aligned(16))) bf16_t Bt[BN * BK];

    // Per-lane fixed staging rows (4 lanes per row, 16B chunks).
    const int r0 = tid >> 2;                 // 0..63
    const int k8 = (tid & 3) * 8;            // element offset of this 16B chunk
    const int n_0 = rowbase + mloc + r0;
    const int n_1 = n_0 + 64;
    const size_t srow0 = (d == 1) ? (size_t)srcrow[n_0] : (size_t)n_0;
    const size_t srow1 = (d == 1) ? (size_t)srcrow[n_1] : (size_t)n_1;
    const bf16_t* Ar0 = A + srow0 * KD + k8;
    const bf16_t* Ar1 = A + srow1 * KD + k8;
    const bf16_t* Br0 = Wp + ((size_t)d * G4 + n0 + r0) * KD + k8;
    const bf16_t* Br1 = Br0 + (size_t)64 * KD;

    f32x4 acc[4][4];
#pragma unroll
    for (int i = 0; i < 4; ++i)
#pragma unroll
        for (int j = 0; j < 4; ++j) { f32x4 z = {0.f, 0.f, 0.f, 0.f}; acc[i][j] = z; }

    for (int kt = 0; kt < KD; kt += BK) {
        __builtin_amdgcn_global_load_lds(AS1(Ar0 + kt), AS3(&At[(wave * 64) * 8]),       16, 0, 0);
        __builtin_amdgcn_global_load_lds(AS1(Ar1 + kt), AS3(&At[(256 + wave * 64) * 8]), 16, 0, 0);
        __builtin_amdgcn_global_load_lds(AS1(Br0 + kt), AS3(&Bt[(wave * 64) * 8]),       16, 0, 0);
        __builtin_amdgcn_global_load_lds(AS1(Br1 + kt), AS3(&Bt[(256 + wave * 64) * 8]), 16, 0, 0);
        __syncthreads();
        bf16x8 af[4], bff[4];
#pragma unroll
        for (int i = 0; i < 4; ++i) {
            af[i]  = *(const bf16x8*)&At[(wm * 64 + i * 16 + fr) * BK + fq * 8];
            bff[i] = *(const bf16x8*)&Bt[(wn * 64 + i * 16 + fr) * BK + fq * 8];
        }
#pragma unroll
        for (int i = 0; i < 4; ++i)
#pragma unroll
            for (int j = 0; j < 4; ++j)
                acc[i][j] = __builtin_amdgcn_mfma_f32_16x16x32_bf16(af[i], bff[j], acc[i][j], 0, 0, 0);
        __syncthreads();
    }

    const int cb = n0 + wn * 64 + fr;
#pragma unroll
    for (int mi = 0; mi < 4; ++mi) {
#pragma unroll
        for (int rr = 0; rr < 4; ++rr) {
            int r = mloc + wm * 64 + mi * 16 + fq * 4 + rr;
            float* prow = PREc + ((size_t)d * TCR + r) * G4;
#pragma unroll
            for (int ni = 0; ni < 4; ++ni) {
                int col = cb + ni * 16;
                prow[col] = acc[mi][ni][rr] + bp[d * G4 + col];
            }
        }
    }
}

// ---------------------------------------------------------------------------
// Persistent cooperative recurrence kernel: runs TC timesteps with grid.sync()
// between steps. Grid (32 unit-groups, 4 m-tiles, 2 dirs) = 256 blocks x 256
// threads = 1 block/CU (64 KiB LDS). Whh slice staged to LDS ONCE, reused all
// steps. c-state and owned-h kept in registers for the whole chunk.
// mode 0: h -> H1 (bf16). mode 1: h -> OUT (f32, masked).
// ---------------------------------------------------------------------------
__global__ __launch_bounds__(256)
void lstm_chunk_kernel(const bf16_t* __restrict__ Whhp,  // (2,2048,512) bf16
                       const float* __restrict__ PREc,   // (2,TCR,2048)
                       const int* __restrict__ F_lens,
                       float* __restrict__ cfb,          // (2,256,512) f32
                       bf16_t* __restrict__ hbA,         // (2,256,512) bf16 (even-t input)
                       bf16_t* __restrict__ hbB,         // (2,256,512) bf16 (odd-t input)
                       bf16_t* __restrict__ H1,          // (32768,1024) bf16 (mode 0)
                       float* __restrict__ OUT,          // (32768,1024) f32  (mode 1)
                       int t0, int TC, int TCR, int mode)
{
    const int d  = blockIdx.z;
    const int bx = blockIdx.x;          // unit group 0..31
    const int m0 = blockIdx.y * 64;
    const int tid = threadIdx.x;
    const int lane = tid & 63, wave = tid >> 6;
    const int fr = lane & 15, fq = lane >> 4;

    __shared__ __attribute__((aligned(16))) bf16_t Bt[64 * 512];   // 64 KiB

    // Stage Whh slice (64 rows x 512 K) once; XOR-swizzled SOURCE, linear dest.
    const bf16_t* Bg = Whhp + ((size_t)d * G4 + bx * 64) * H_DIM;
#pragma unroll
    for (int it = 0; it < 16; ++it) {
        int c   = it * 256 + tid;
        int row = c >> 6, ck = c & 63;
        int cks = ck ^ (row & 7);
        __builtin_amdgcn_global_load_lds(AS1(Bg + (size_t)row * H_DIM + cks * 8),
                                         AS3(&Bt[(it * 256 + wave * 64) * 8]), 16, 0, 0);
    }

    // Per-lane constants (lane owns unit u for 4 fixed m-rows, all steps).
    const int mrow  = m0 + wave * 16 + fr;     // A-fragment row
    const int u     = bx * 16 + fr;
    const int cbcol = bx * 64 + fr;
    int mm[4], LL[4], sidx[4];
    float c_own[4], h_own[4];
    const float* pbase[4];
#pragma unroll
    for (int rr = 0; rr < 4; ++rr) {
        mm[rr]   = m0 + wave * 16 + fq * 4 + rr;
        LL[rr]   = F_lens[mm[rr]];
        sidx[rr] = (d * M_B + mm[rr]) * H_DIM + u;
        c_own[rr]= cfb[sidx[rr]];
        pbase[rr]= PREc + ((size_t)d * TCR + mm[rr]) * G4 + cbcol;
    }
    const bf16_t* hin0 = (t0 & 1) ? hbB : hbA;
#pragma unroll
    for (int rr = 0; rr < 4; ++rr) h_own[rr] = (float)hin0[sidx[rr]];

    __syncthreads();   // drains staging (vmcnt 0 before barrier)

    cg::grid_group grid = cg::this_grid();

    for (int tt = 0; tt < TC; ++tt) {
        const int t = t0 + tt;
        const bf16_t* hin  = (t & 1) ? hbB : hbA;
        bf16_t*       hout = (t & 1) ? hbA : hbB;

        // PRE loads for this step (independent of h) — issue before MFMA.
        float pv[4][4];
#pragma unroll
        for (int rr = 0; rr < 4; ++rr) {
            const float* prow = pbase[rr] + (size_t)tt * ((size_t)M_B * G4);
            pv[rr][0] = prow[0];
            pv[rr][1] = prow[16];
            pv[rr][2] = prow[32];
            pv[rr][3] = prow[48];
        }

        // h fragments for this step.
        const bf16_t* Arow = hin + ((size_t)d * M_B + mrow) * H_DIM + fq * 8;
        bf16x8 af[16];
#pragma unroll
        for (int ks = 0; ks < 16; ++ks)
            af[ks] = *(const bf16x8*)(Arow + ks * 32);

        f32x4 acc[4];
#pragma unroll
        for (int j = 0; j < 4; ++j) { f32x4 z = {0.f, 0.f, 0.f, 0.f}; acc[j] = z; }

#pragma unroll
        for (int ks = 0; ks < 16; ++ks) {
#pragma unroll
            for (int j = 0; j < 4; ++j) {
                int rb = j * 16 + fr;
                int ck = (ks * 4 + fq) ^ (rb & 7);
                bf16x8 bf = *(const bf16x8*)&Bt[rb * 512 + ck * 8];
                acc[j] = __builtin_amdgcn_mfma_f32_16x16x32_bf16(af[ks], bf, acc[j], 0, 0, 0);
            }
        }

        // Fused LSTM cell epilogue.
#pragma unroll
        for (int rr = 0; rr < 4; ++rr) {
            bool mt = (t < LL[rr]);
            float gi = acc[0][rr] + pv[rr][0];
            float gf = acc[1][rr] + pv[rr][1];
            float gg = acc[2][rr] + pv[rr][2];
            float go = acc[3][rr] + pv[rr][3];
            float c2 = sigm(gf) * c_own[rr] + sigm(gi) * tanhfast(gg);
            float h2 = sigm(go) * tanhfast(c2);
            if (!mt) { c2 = c_own[rr]; h2 = h_own[rr]; }
            c_own[rr] = c2;
            h_own[rr] = h2;
            hout[sidx[rr]] = (bf16_t)h2;
            int trow = (d == 0 || !mt) ? t : (LL[rr] - 1 - t);
            size_t orow = (size_t)trow * M_B + mm[rr];
            if (mode == 0) H1[orow * 1024 + d * H_DIM + u] = (bf16_t)h2;
            else           OUT[orow * 1024 + d * H_DIM + u] = mt ? h2 : 0.f;
        }

        __threadfence();
        grid.sync();
    }

#pragma unroll
    for (int rr = 0; rr < 4; ++rr) cfb[sidx[rr]] = c_own[rr];
}

// ---------------------------------------------------------------------------
extern "C" void kernel_launch(void* const* d_in, const int* in_sizes, int n_in,
                              void* d_out, int out_size, void* d_ws, size_t ws_size,
                              hipStream_t stream)
{
    const int*   F      = (const int*)d_in[0];
    const int*   F_lens = (const int*)d_in[1];
    const float* emb    = (const float*)d_in[2];
    const float* Wih0   = (const float*)d_in[3];
    const float* Whh0   = (const float*)d_in[4];
    const float* b0     = (const float*)d_in[5];
    const float* Wih1   = (const float*)d_in[6];
    const float* Whh1   = (const float*)d_in[7];
    const float* b1     = (const float*)d_in[8];
    float* OUT = (float*)d_out;

    // Base workspace (~155 MiB), 256B-aligned blocks.
    char* p = (char*)d_ws;
    auto alloc = [&](size_t bytes) { char* q = p; p += (bytes + 255) & ~(size_t)255; return (void*)q; };
    bf16_t* X0    = (bf16_t*)alloc((size_t)N_ROWS * E_DIM * 2);   // 64 MiB
    bf16_t* H1    = (bf16_t*)alloc((size_t)N_ROWS * 1024 * 2);    // 64 MiB
    bf16_t* Wih0p = (bf16_t*)alloc((size_t)2 * G4 * E_DIM * 2);   // 8 MiB
    bf16_t* Whh0p = (bf16_t*)alloc((size_t)2 * G4 * H_DIM * 2);   // 4 MiB
    bf16_t* Wih1p = (bf16_t*)alloc((size_t)2 * G4 * E_DIM * 2);   // 8 MiB
    bf16_t* Whh1p = (bf16_t*)alloc((size_t)2 * G4 * H_DIM * 2);   // 4 MiB
    float*  b0p   = (float*)alloc((size_t)2 * G4 * 4);
    float*  b1p   = (float*)alloc((size_t)2 * G4 * 4);
    int*    srcrow= (int*)alloc((size_t)N_ROWS * 4);              // 128 KiB
    bf16_t* hbA   = (bf16_t*)alloc((size_t)2 * M_B * H_DIM * 2);
    bf16_t* hbB   = (bf16_t*)alloc((size_t)2 * M_B * H_DIM * 2);
    float*  cfb   = (float*)alloc((size_t)2 * M_B * H_DIM * 4);
    size_t base_used = (size_t)(p - (char*)d_ws);

    // Largest time-chunk whose f32 PRE buffer fits the remaining workspace.
    int TC = 0;
    const int tcs[8] = {128, 64, 32, 16, 8, 4, 2, 1};
    for (int i = 0; i < 8; ++i) {
        size_t need = base_used + (size_t)2 * tcs[i] * M_B * G4 * 4;
        if (need <= ws_size) { TC = tcs[i]; break; }
    }
    if (TC == 0) return;  // cannot run at all
    float* PREc = (float*)p;
    const int TCR = TC * M_B;

    permute_weights_kernel<<<dim3(2 * G4), 256, 0, stream>>>(Wih0, Whh0, b0, Wih0p, Whh0p, b0p);
    permute_weights_kernel<<<dim3(2 * G4), 256, 0, stream>>>(Wih1, Whh1, b1, Wih1p, Whh1p, b1p);
    embed_kernel<<<dim3(N_ROWS), 256, 0, stream>>>(F, emb, X0);
    rowmap_kernel<<<dim3(N_ROWS / 256), 256, 0, stream>>>(F_lens, srcrow);

    for (int layer = 0; layer < 2; ++layer) {
        const bf16_t* Xin  = layer ? H1 : X0;
        const bf16_t* Wihp = layer ? Wih1p : Wih0p;
        const bf16_t* Whhp = layer ? Whh1p : Whh0p;
        const float*  bp   = layer ? b1p : b0p;

        hipMemsetAsync(hbA, 0, (size_t)2 * M_B * H_DIM * 2, stream);
        hipMemsetAsync(cfb, 0, (size_t)2 * M_B * H_DIM * 4, stream);

        for (int c = 0; c < S_LEN / TC; ++c) {
            gemm_pre_kernel<<<dim3(G4 / BN, TCR / BM, 2), 256, 0, stream>>>(
                Xin, Wihp, bp, srcrow, PREc, c * TCR, TCR);

            int t0v = c * TC, TCv = TC, TCRv = TCR, modev = layer;
            const bf16_t* Whhp_v = Whhp;
            const float*  PREc_v = PREc;
            const int*    Flen_v = F_lens;
            float*        cfb_v  = cfb;
            bf16_t*       hbA_v  = hbA;
            bf16_t*       hbB_v  = hbB;
            bf16_t*       H1_v   = H1;
            float*        OUT_v  = OUT;
            void* kargs[12] = {
                (void*)&Whhp_v, (void*)&PREc_v, (void*)&Flen_v, (void*)&cfb_v,
                (void*)&hbA_v, (void*)&hbB_v, (void*)&H1_v, (void*)&OUT_v,
                (void*)&t0v, (void*)&TCv, (void*)&TCRv, (void*)&modev
            };
            hipLaunchCooperativeKernel((void*)lstm_chunk_kernel,
                                       dim3(32, 4, 2), dim3(256, 1, 1),
                                       kargs, 0, stream);
        }
    }
}

// Round 4
// 3777.685 us; speedup vs baseline: 4.6188x; 4.6188x over previous
//
#include <hip/hip_runtime.h>
#include <hip/hip_bf16.h>

// Problem dims
#define S_LEN 128
#define M_B   256
#define E_DIM 1024
#define H_DIM 512
#define G4    2048          // 4*H
#define N_ROWS (S_LEN*M_B)  // 32768
#define KD    1024          // GEMM K for both layers (E = 2H = 1024)

typedef __bf16 bf16_t;
typedef __bf16 bf16x8 __attribute__((ext_vector_type(8)));
typedef float  f32x4  __attribute__((ext_vector_type(4)));
typedef int    i32x4  __attribute__((ext_vector_type(4)));

#define AS1(p) ((const __attribute__((address_space(1))) void*)(p))
#define AS3(p) ((__attribute__((address_space(3))) void*)(p))

__device__ __forceinline__ float sigm(float x)     { return 1.f / (1.f + __expf(-x)); }
__device__ __forceinline__ float tanhfast(float x) { return 2.f / (1.f + __expf(-2.f * x)) - 1.f; }

// Device-scope (LLC) h exchange: write-through stores, cache-bypassing loads.
__device__ __forceinline__ void store_h_dev(bf16_t* p, bf16_t v) {
    unsigned int w = (unsigned int)__builtin_bit_cast(unsigned short, v);
    asm volatile("global_store_short %0, %1, off sc0 sc1" :: "v"(p), "v"(w) : "memory");
}
__device__ __forceinline__ bf16x8 load_h_dev(const bf16_t* p) {
    i32x4 r;
    asm volatile("global_load_dwordx4 %0, %1, off sc0 sc1" : "=v"(r) : "v"(p) : "memory");
    return __builtin_bit_cast(bf16x8, r);
}

// ---------------------------------------------------------------------------
// Weight permutation + bf16 conversion.
// Gate permutation: j' = q*64 + gate*16 + u16  <->  j = gate*512 + (q*16+u16)
// ---------------------------------------------------------------------------
__global__ __launch_bounds__(256)
void permute_weights_kernel(const float* __restrict__ Wih, const float* __restrict__ Whh,
                            const float* __restrict__ b,
                            bf16_t* __restrict__ Wihp, bf16_t* __restrict__ Whhp,
                            float* __restrict__ bp)
{
    int bid = blockIdx.x;            // d*2048 + jp
    int d  = bid >> 11;
    int jp = bid & 2047;
    int q = jp >> 6, r = jp & 63;
    int gate = r >> 4, u16 = r & 15;
    int j = gate * H_DIM + q * 16 + u16;

    const float* s_ih = Wih + ((size_t)d * G4 + j) * E_DIM;
    bf16_t*      d_ih = Wihp + ((size_t)d * G4 + jp) * E_DIM;
    for (int e = threadIdx.x; e < E_DIM; e += 256) d_ih[e] = (bf16_t)s_ih[e];

    const float* s_hh = Whh + ((size_t)d * G4 + j) * H_DIM;
    bf16_t*      d_hh = Whhp + ((size_t)d * G4 + jp) * H_DIM;
    for (int k = threadIdx.x; k < H_DIM; k += 256) d_hh[k] = (bf16_t)s_hh[k];

    if (threadIdx.x == 0) bp[d * G4 + jp] = b[d * G4 + j];
}

// ---------------------------------------------------------------------------
// Embedding lookup -> bf16 X (32768 x 1024). emb[PAD_ID] is zero.
// ---------------------------------------------------------------------------
__global__ __launch_bounds__(256)
void embed_kernel(const int* __restrict__ F, const float* __restrict__ emb,
                  bf16_t* __restrict__ X)
{
    int n   = blockIdx.x;            // t*256 + m
    int tok = F[n];
    const float4* src = (const float4*)(emb + (size_t)tok * E_DIM);
    bf16_t*       dst = X + (size_t)n * E_DIM;
    for (int i = threadIdx.x; i < E_DIM / 4; i += 256) {
        float4 v = src[i];
        dst[i * 4 + 0] = (bf16_t)v.x;
        dst[i * 4 + 1] = (bf16_t)v.y;
        dst[i * 4 + 2] = (bf16_t)v.z;
        dst[i * 4 + 3] = (bf16_t)v.w;
    }
}

// ---------------------------------------------------------------------------
// srcrow[t*256+m] = ((t < L) ? L-1-t : t) * 256 + m   (self-inverse gather)
// ---------------------------------------------------------------------------
__global__ __launch_bounds__(256)
void rowmap_kernel(const int* __restrict__ F_lens, int* __restrict__ srcrow)
{
    int n = blockIdx.x * 256 + threadIdx.x;
    int t = n >> 8, m = n & 255;
    int L = F_lens[m];
    int st = (t < L) ? (L - 1 - t) : t;
    srcrow[n] = st * M_B + m;
}

// ---------------------------------------------------------------------------
// Chunked input-projection GEMM (unchanged from round 2).
// ---------------------------------------------------------------------------
#define BM 128
#define BN 128
#define BK 32

__global__ __launch_bounds__(256)
void gemm_pre_kernel(const bf16_t* __restrict__ A,    // (32768, 1024) bf16
                     const bf16_t* __restrict__ Wp,   // (2, 2048, 1024) bf16
                     const float* __restrict__ bp,    // (2, 2048)
                     const int* __restrict__ srcrow,  // (32768)
                     float* __restrict__ PREc,        // (2, TCR, 2048)
                     int rowbase, int TCR)
{
    const int d    = blockIdx.z;
    const int n0   = blockIdx.x * BN;
    const int mloc = blockIdx.y * BM;
    const int tid  = threadIdx.x;
    const int lane = tid & 63, wave = tid >> 6;
    const int wm = wave >> 1, wn = wave & 1;
    const int fr = lane & 15, fq = lane >> 4;

    __shared__ __attribute__((aligned(16))) bf16_t At[BM * BK];
    __shared__ __attribute__((aligned(16))) bf16_t Bt[BN * BK];

    const int r0 = tid >> 2;
    const int k8 = (tid & 3) * 8;
    const int n_0 = rowbase + mloc + r0;
    const int n_1 = n_0 + 64;
    const size_t srow0 = (d == 1) ? (size_t)srcrow[n_0] : (size_t)n_0;
    const size_t srow1 = (d == 1) ? (size_t)srcrow[n_1] : (size_t)n_1;
    const bf16_t* Ar0 = A + srow0 * KD + k8;
    const bf16_t* Ar1 = A + srow1 * KD + k8;
    const bf16_t* Br0 = Wp + ((size_t)d * G4 + n0 + r0) * KD + k8;
    const bf16_t* Br1 = Br0 + (size_t)64 * KD;

    f32x4 acc[4][4];
#pragma unroll
    for (int i = 0; i < 4; ++i)
#pragma unroll
        for (int j = 0; j < 4; ++j) { f32x4 z = {0.f, 0.f, 0.f, 0.f}; acc[i][j] = z; }

    for (int kt = 0; kt < KD; kt += BK) {
        __builtin_amdgcn_global_load_lds(AS1(Ar0 + kt), AS3(&At[(wave * 64) * 8]),       16, 0, 0);
        __builtin_amdgcn_global_load_lds(AS1(Ar1 + kt), AS3(&At[(256 + wave * 64) * 8]), 16, 0, 0);
        __builtin_amdgcn_global_load_lds(AS1(Br0 + kt), AS3(&Bt[(wave * 64) * 8]),       16, 0, 0);
        __builtin_amdgcn_global_load_lds(AS1(Br1 + kt), AS3(&Bt[(256 + wave * 64) * 8]), 16, 0, 0);
        __syncthreads();
        bf16x8 af[4], bff[4];
#pragma unroll
        for (int i = 0; i < 4; ++i) {
            af[i]  = *(const bf16x8*)&At[(wm * 64 + i * 16 + fr) * BK + fq * 8];
            bff[i] = *(const bf16x8*)&Bt[(wn * 64 + i * 16 + fr) * BK + fq * 8];
        }
#pragma unroll
        for (int i = 0; i < 4; ++i)
#pragma unroll
            for (int j = 0; j < 4; ++j)
                acc[i][j] = __builtin_amdgcn_mfma_f32_16x16x32_bf16(af[i], bff[j], acc[i][j], 0, 0, 0);
        __syncthreads();
    }

    const int cb = n0 + wn * 64 + fr;
#pragma unroll
    for (int mi = 0; mi < 4; ++mi) {
#pragma unroll
        for (int rr = 0; rr < 4; ++rr) {
            int r = mloc + wm * 64 + mi * 16 + fq * 4 + rr;
            float* prow = PREc + ((size_t)d * TCR + r) * G4;
#pragma unroll
            for (int ni = 0; ni < 4; ++ni) {
                int col = cb + ni * 16;
                prow[col] = acc[mi][ni][rr] + bp[d * G4 + col];
            }
        }
    }
}

// ---------------------------------------------------------------------------
// Persistent recurrence kernel with hand-rolled grid barrier (no L2 flush):
// h exchanged via device-scope write-through stores + cache-bypassing loads;
// barrier = monotonic agent-scope atomic counter (RELAXED, no wbl2/inv).
// Grid (32 unit-groups, 4 m-tiles, 2 dirs) = 256 blocks x 256 threads.
// ---------------------------------------------------------------------------
__global__ __launch_bounds__(256)
void lstm_chunk_kernel(const bf16_t* __restrict__ Whhp,  // (2,2048,512) bf16
                       const float* __restrict__ PREc,   // (2,TCR,2048)
                       const int* __restrict__ F_lens,
                       float* __restrict__ cfb,          // (2,256,512) f32
                       bf16_t* __restrict__ hbA,         // (2,256,512) bf16
                       bf16_t* __restrict__ hbB,         // (2,256,512) bf16
                       bf16_t* __restrict__ H1,          // (32768,1024) bf16 (mode 0)
                       float* __restrict__ OUT,          // (32768,1024) f32  (mode 1)
                       unsigned int* __restrict__ ctr,   // grid-barrier counter
                       int t0, int TC, int TCR, int mode, int s_base)
{
    const int d  = blockIdx.z;
    const int bx = blockIdx.x;          // unit group 0..31
    const int m0 = blockIdx.y * 64;
    const int tid = threadIdx.x;
    const int lane = tid & 63, wave = tid >> 6;
    const int fr = lane & 15, fq = lane >> 4;

    __shared__ __attribute__((aligned(16))) bf16_t Bt[64 * 512];   // 64 KiB

    // Stage Whh slice (64 rows x 512 K) once; XOR-swizzled SOURCE, linear dest.
    const bf16_t* Bg = Whhp + ((size_t)d * G4 + bx * 64) * H_DIM;
#pragma unroll
    for (int it = 0; it < 16; ++it) {
        int c   = it * 256 + tid;
        int row = c >> 6, ck = c & 63;
        int cks = ck ^ (row & 7);
        __builtin_amdgcn_global_load_lds(AS1(Bg + (size_t)row * H_DIM + cks * 8),
                                         AS3(&Bt[(it * 256 + wave * 64) * 8]), 16, 0, 0);
    }

    // Per-lane constants (lane owns unit u for 4 fixed m-rows, all steps).
    const int mrow  = m0 + wave * 16 + fr;     // A-fragment row
    const int u     = bx * 16 + fr;
    const int cbcol = bx * 64 + fr;
    int mm[4], LL[4], sidx[4];
    float c_own[4], h_own[4];
    const float* pbase[4];
#pragma unroll
    for (int rr = 0; rr < 4; ++rr) {
        mm[rr]   = m0 + wave * 16 + fq * 4 + rr;
        LL[rr]   = F_lens[mm[rr]];
        sidx[rr] = (d * M_B + mm[rr]) * H_DIM + u;
        c_own[rr]= cfb[sidx[rr]];
        pbase[rr]= PREc + ((size_t)d * TCR + mm[rr]) * G4 + cbcol;
    }
    {
        const bf16_t* hin0 = (t0 & 1) ? hbB : hbA;
#pragma unroll
        for (int rr = 0; rr < 4; ++rr) h_own[rr] = (float)hin0[sidx[rr]];
    }

    __syncthreads();   // staging drained (compiler emits vmcnt0 before barrier)

    for (int tt = 0; tt < TC; ++tt) {
        const int t = t0 + tt;
        const bf16_t* hin  = (t & 1) ? hbB : hbA;
        bf16_t*       hout = (t & 1) ? hbA : hbB;

        // PRE loads for this step (HBM; independent of h) — issue first.
        float pv[4][4];
#pragma unroll
        for (int rr = 0; rr < 4; ++rr) {
            const float* prow = pbase[rr] + (size_t)tt * ((size_t)M_B * G4);
            pv[rr][0] = prow[0];
            pv[rr][1] = prow[16];
            pv[rr][2] = prow[32];
            pv[rr][3] = prow[48];
        }

        // h fragments (device-scope, bypass L1/L2 -> LLC where producers wrote).
        const bf16_t* Arow = hin + ((size_t)d * M_B + mrow) * H_DIM + fq * 8;
        bf16x8 af[16];
#pragma unroll
        for (int ks = 0; ks < 16; ++ks)
            af[ks] = load_h_dev(Arow + ks * 32);
        asm volatile("s_waitcnt vmcnt(0)" ::: "memory");
        __builtin_amdgcn_sched_barrier(0);

        f32x4 acc[4];
#pragma unroll
        for (int j = 0; j < 4; ++j) { f32x4 z = {0.f, 0.f, 0.f, 0.f}; acc[j] = z; }

#pragma unroll
        for (int ks = 0; ks < 16; ++ks) {
#pragma unroll
            for (int j = 0; j < 4; ++j) {
                int rb = j * 16 + fr;
                int ck = (ks * 4 + fq) ^ (rb & 7);
                bf16x8 bf = *(const bf16x8*)&Bt[rb * 512 + ck * 8];
                acc[j] = __builtin_amdgcn_mfma_f32_16x16x32_bf16(af[ks], bf, acc[j], 0, 0, 0);
            }
        }

        // Fused LSTM cell epilogue.
#pragma unroll
        for (int rr = 0; rr < 4; ++rr) {
            bool mt = (t < LL[rr]);
            float gi = acc[0][rr] + pv[rr][0];
            float gf = acc[1][rr] + pv[rr][1];
            float gg = acc[2][rr] + pv[rr][2];
            float go = acc[3][rr] + pv[rr][3];
            float c2 = sigm(gf) * c_own[rr] + sigm(gi) * tanhfast(gg);
            float h2 = sigm(go) * tanhfast(c2);
            if (!mt) { c2 = c_own[rr]; h2 = h_own[rr]; }
            c_own[rr] = c2;
            h_own[rr] = h2;
            store_h_dev(&hout[sidx[rr]], (bf16_t)h2);       // device-visible
            int trow = (d == 0 || !mt) ? t : (LL[rr] - 1 - t);
            size_t orow = (size_t)trow * M_B + mm[rr];
            if (mode == 0) H1[orow * 1024 + d * H_DIM + u] = (bf16_t)h2;
            else           OUT[orow * 1024 + d * H_DIM + u] = mt ? h2 : 0.f;
        }

        // Hand-rolled grid barrier (monotonic counter, RELAXED agent scope).
        asm volatile("s_waitcnt vmcnt(0)" ::: "memory");  // per-wave drain of h stores
        __syncthreads();                                  // block-wide drain
        if (tid == 0) {
            __hip_atomic_fetch_add(ctr, 1u, __ATOMIC_RELAXED, __HIP_MEMORY_SCOPE_AGENT);
            unsigned int tgt = (unsigned int)(s_base + tt + 1) * 256u;
            while (__hip_atomic_load(ctr, __ATOMIC_RELAXED, __HIP_MEMORY_SCOPE_AGENT) < tgt)
                __builtin_amdgcn_s_sleep(4);
        }
        __syncthreads();
    }

#pragma unroll
    for (int rr = 0; rr < 4; ++rr) cfb[sidx[rr]] = c_own[rr];
}

// ---------------------------------------------------------------------------
extern "C" void kernel_launch(void* const* d_in, const int* in_sizes, int n_in,
                              void* d_out, int out_size, void* d_ws, size_t ws_size,
                              hipStream_t stream)
{
    const int*   F      = (const int*)d_in[0];
    const int*   F_lens = (const int*)d_in[1];
    const float* emb    = (const float*)d_in[2];
    const float* Wih0   = (const float*)d_in[3];
    const float* Whh0   = (const float*)d_in[4];
    const float* b0     = (const float*)d_in[5];
    const float* Wih1   = (const float*)d_in[6];
    const float* Whh1   = (const float*)d_in[7];
    const float* b1     = (const float*)d_in[8];
    float* OUT = (float*)d_out;

    // Base workspace (~155 MiB), 256B-aligned blocks.
    char* p = (char*)d_ws;
    auto alloc = [&](size_t bytes) { char* q = p; p += (bytes + 255) & ~(size_t)255; return (void*)q; };
    bf16_t* X0    = (bf16_t*)alloc((size_t)N_ROWS * E_DIM * 2);   // 64 MiB
    bf16_t* H1    = (bf16_t*)alloc((size_t)N_ROWS * 1024 * 2);    // 64 MiB
    bf16_t* Wih0p = (bf16_t*)alloc((size_t)2 * G4 * E_DIM * 2);   // 8 MiB
    bf16_t* Whh0p = (bf16_t*)alloc((size_t)2 * G4 * H_DIM * 2);   // 4 MiB
    bf16_t* Wih1p = (bf16_t*)alloc((size_t)2 * G4 * E_DIM * 2);   // 8 MiB
    bf16_t* Whh1p = (bf16_t*)alloc((size_t)2 * G4 * H_DIM * 2);   // 4 MiB
    float*  b0p   = (float*)alloc((size_t)2 * G4 * 4);
    float*  b1p   = (float*)alloc((size_t)2 * G4 * 4);
    int*    srcrow= (int*)alloc((size_t)N_ROWS * 4);              // 128 KiB
    bf16_t* hbA   = (bf16_t*)alloc((size_t)2 * M_B * H_DIM * 2);
    bf16_t* hbB   = (bf16_t*)alloc((size_t)2 * M_B * H_DIM * 2);
    float*  cfb   = (float*)alloc((size_t)2 * M_B * H_DIM * 4);
    unsigned int* ctr = (unsigned int*)alloc(256);
    size_t base_used = (size_t)(p - (char*)d_ws);

    // Largest time-chunk whose f32 PRE buffer fits the remaining workspace.
    int TC = 0;
    const int tcs[8] = {128, 64, 32, 16, 8, 4, 2, 1};
    for (int i = 0; i < 8; ++i) {
        size_t need = base_used + (size_t)2 * tcs[i] * M_B * G4 * 4;
        if (need <= ws_size) { TC = tcs[i]; break; }
    }
    if (TC == 0) return;  // cannot run at all
    float* PREc = (float*)p;
    const int TCR = TC * M_B;

    hipMemsetAsync(ctr, 0, 256, stream);
    permute_weights_kernel<<<dim3(2 * G4), 256, 0, stream>>>(Wih0, Whh0, b0, Wih0p, Whh0p, b0p);
    permute_weights_kernel<<<dim3(2 * G4), 256, 0, stream>>>(Wih1, Whh1, b1, Wih1p, Whh1p, b1p);
    embed_kernel<<<dim3(N_ROWS), 256, 0, stream>>>(F, emb, X0);
    rowmap_kernel<<<dim3(N_ROWS / 256), 256, 0, stream>>>(F_lens, srcrow);

    for (int layer = 0; layer < 2; ++layer) {
        const bf16_t* Xin  = layer ? H1 : X0;
        const bf16_t* Wihp = layer ? Wih1p : Wih0p;
        const bf16_t* Whhp = layer ? Whh1p : Whh0p;
        const float*  bp   = layer ? b1p : b0p;

        hipMemsetAsync(hbA, 0, (size_t)2 * M_B * H_DIM * 2, stream);
        hipMemsetAsync(cfb, 0, (size_t)2 * M_B * H_DIM * 4, stream);

        for (int c = 0; c < S_LEN / TC; ++c) {
            gemm_pre_kernel<<<dim3(G4 / BN, TCR / BM, 2), 256, 0, stream>>>(
                Xin, Wihp, bp, srcrow, PREc, c * TCR, TCR);

            int t0v = c * TC, TCv = TC, TCRv = TCR, modev = layer;
            int s_basev = layer * S_LEN + c * TC;
            const bf16_t* Whhp_v = Whhp;
            const float*  PREc_v = PREc;
            const int*    Flen_v = F_lens;
            float*        cfb_v  = cfb;
            bf16_t*       hbA_v  = hbA;
            bf16_t*       hbB_v  = hbB;
            bf16_t*       H1_v   = H1;
            float*        OUT_v  = OUT;
            unsigned int* ctr_v  = ctr;
            void* kargs[14] = {
                (void*)&Whhp_v, (void*)&PREc_v, (void*)&Flen_v, (void*)&cfb_v,
                (void*)&hbA_v, (void*)&hbB_v, (void*)&H1_v, (void*)&OUT_v,
                (void*)&ctr_v, (void*)&t0v, (void*)&TCv, (void*)&TCRv,
                (void*)&modev, (void*)&s_basev
            };
            hipLaunchCooperativeKernel((void*)lstm_chunk_kernel,
                                       dim3(32, 4, 2), dim3(256, 1, 1),
                                       kargs, 0, stream);
        }
    }
}

// Round 5
// 2641.278 us; speedup vs baseline: 6.6060x; 1.4302x over previous
//
#include <hip/hip_runtime.h>
#include <hip/hip_bf16.h>

// Problem dims
#define S_LEN 128
#define M_B   256
#define E_DIM 1024
#define H_DIM 512
#define G4    2048          // 4*H
#define N_ROWS (S_LEN*M_B)  // 32768
#define KD    1024          // GEMM K for both layers (E = 2H = 1024)

typedef __bf16 bf16_t;
typedef __bf16 bf16x8 __attribute__((ext_vector_type(8)));
typedef float  f32x4  __attribute__((ext_vector_type(4)));
typedef int    i32x4  __attribute__((ext_vector_type(4)));

#define AS1(p) ((const __attribute__((address_space(1))) void*)(p))
#define AS3(p) ((__attribute__((address_space(3))) void*)(p))

__device__ __forceinline__ float sigm(float x)     { return 1.f / (1.f + __expf(-x)); }
__device__ __forceinline__ float tanhfast(float x) { return 2.f / (1.f + __expf(-2.f * x)) - 1.f; }

// Device-scope (LLC) h exchange: write-through stores, cache-bypassing loads.
__device__ __forceinline__ void store_h_dev(bf16_t* p, bf16_t v) {
    unsigned int w = (unsigned int)__builtin_bit_cast(unsigned short, v);
    asm volatile("global_store_short %0, %1, off sc0 sc1" :: "v"(p), "v"(w) : "memory");
}
__device__ __forceinline__ bf16x8 load_h_dev(const bf16_t* p) {
    i32x4 r;
    asm volatile("global_load_dwordx4 %0, %1, off sc0 sc1" : "=v"(r) : "v"(p) : "memory");
    return __builtin_bit_cast(bf16x8, r);
}
// Plain f32 load via asm: issues where written (not sunk to use point).
__device__ __forceinline__ float load_f32_async(const float* p) {
    float r;
    asm volatile("global_load_dword %0, %1, off" : "=v"(r) : "v"(p) : "memory");
    return r;
}

// ---------------------------------------------------------------------------
// Weight permutation + bf16 conversion.
// Gate permutation: j' = q*64 + gate*16 + u16  <->  j = gate*512 + (q*16+u16)
// ---------------------------------------------------------------------------
__global__ __launch_bounds__(256)
void permute_weights_kernel(const float* __restrict__ Wih, const float* __restrict__ Whh,
                            const float* __restrict__ b,
                            bf16_t* __restrict__ Wihp, bf16_t* __restrict__ Whhp,
                            float* __restrict__ bp)
{
    int bid = blockIdx.x;            // d*2048 + jp
    int d  = bid >> 11;
    int jp = bid & 2047;
    int q = jp >> 6, r = jp & 63;
    int gate = r >> 4, u16 = r & 15;
    int j = gate * H_DIM + q * 16 + u16;

    const float* s_ih = Wih + ((size_t)d * G4 + j) * E_DIM;
    bf16_t*      d_ih = Wihp + ((size_t)d * G4 + jp) * E_DIM;
    for (int e = threadIdx.x; e < E_DIM; e += 256) d_ih[e] = (bf16_t)s_ih[e];

    const float* s_hh = Whh + ((size_t)d * G4 + j) * H_DIM;
    bf16_t*      d_hh = Whhp + ((size_t)d * G4 + jp) * H_DIM;
    for (int k = threadIdx.x; k < H_DIM; k += 256) d_hh[k] = (bf16_t)s_hh[k];

    if (threadIdx.x == 0) bp[d * G4 + jp] = b[d * G4 + j];
}

// ---------------------------------------------------------------------------
// Embedding lookup -> bf16 X (32768 x 1024). emb[PAD_ID] is zero.
// ---------------------------------------------------------------------------
__global__ __launch_bounds__(256)
void embed_kernel(const int* __restrict__ F, const float* __restrict__ emb,
                  bf16_t* __restrict__ X)
{
    int n   = blockIdx.x;            // t*256 + m
    int tok = F[n];
    const float4* src = (const float4*)(emb + (size_t)tok * E_DIM);
    bf16_t*       dst = X + (size_t)n * E_DIM;
    for (int i = threadIdx.x; i < E_DIM / 4; i += 256) {
        float4 v = src[i];
        dst[i * 4 + 0] = (bf16_t)v.x;
        dst[i * 4 + 1] = (bf16_t)v.y;
        dst[i * 4 + 2] = (bf16_t)v.z;
        dst[i * 4 + 3] = (bf16_t)v.w;
    }
}

// ---------------------------------------------------------------------------
// srcrow[t*256+m] = ((t < L) ? L-1-t : t) * 256 + m   (self-inverse gather)
// ---------------------------------------------------------------------------
__global__ __launch_bounds__(256)
void rowmap_kernel(const int* __restrict__ F_lens, int* __restrict__ srcrow)
{
    int n = blockIdx.x * 256 + threadIdx.x;
    int t = n >> 8, m = n & 255;
    int L = F_lens[m];
    int st = (t < L) ? (L - 1 - t) : t;
    srcrow[n] = st * M_B + m;
}

// ---------------------------------------------------------------------------
// Chunked input-projection GEMM with XCD-chunked block swizzle.
// 1-D grid, nwg = 2 * (TCR/BM) * 16 (divisible by 8). Per-XCD contiguous wg
// range: 16 consecutive wg share one A-tile; B panel (4 MiB/dir) L2-resident.
// ---------------------------------------------------------------------------
#define BM 128
#define BN 128
#define BK 32

__global__ __launch_bounds__(256)
void gemm_pre_kernel(const bf16_t* __restrict__ A,    // (32768, 1024) bf16
                     const bf16_t* __restrict__ Wp,   // (2, 2048, 1024) bf16
                     const float* __restrict__ bp,    // (2, 2048)
                     const int* __restrict__ srcrow,  // (32768)
                     float* __restrict__ PREc,        // (2, TCR, 2048)
                     int rowbase, int TCR)
{
    // Bijective XCD-chunk swizzle (nwg % 8 == 0).
    const int nwg = gridDim.x;
    const int qx  = nwg >> 3;
    const int orig = blockIdx.x;
    const int wg   = (orig & 7) * qx + (orig >> 3);
    const int MT   = TCR / BM;
    const int n_t  = wg & 15;
    const int m_t  = (wg >> 4) % MT;
    const int d    = wg / (16 * MT);

    const int n0   = n_t * BN;
    const int mloc = m_t * BM;
    const int tid  = threadIdx.x;
    const int lane = tid & 63, wave = tid >> 6;
    const int wm = wave >> 1, wn = wave & 1;
    const int fr = lane & 15, fq = lane >> 4;

    __shared__ __attribute__((aligned(16))) bf16_t At[BM * BK];
    __shared__ __attribute__((aligned(16))) bf16_t Bt[BN * BK];

    const int r0 = tid >> 2;
    const int k8 = (tid & 3) * 8;
    const int n_0 = rowbase + mloc + r0;
    const int n_1 = n_0 + 64;
    const size_t srow0 = (d == 1) ? (size_t)srcrow[n_0] : (size_t)n_0;
    const size_t srow1 = (d == 1) ? (size_t)srcrow[n_1] : (size_t)n_1;
    const bf16_t* Ar0 = A + srow0 * KD + k8;
    const bf16_t* Ar1 = A + srow1 * KD + k8;
    const bf16_t* Br0 = Wp + ((size_t)d * G4 + n0 + r0) * KD + k8;
    const bf16_t* Br1 = Br0 + (size_t)64 * KD;

    f32x4 acc[4][4];
#pragma unroll
    for (int i = 0; i < 4; ++i)
#pragma unroll
        for (int j = 0; j < 4; ++j) { f32x4 z = {0.f, 0.f, 0.f, 0.f}; acc[i][j] = z; }

    for (int kt = 0; kt < KD; kt += BK) {
        __builtin_amdgcn_global_load_lds(AS1(Ar0 + kt), AS3(&At[(wave * 64) * 8]),       16, 0, 0);
        __builtin_amdgcn_global_load_lds(AS1(Ar1 + kt), AS3(&At[(256 + wave * 64) * 8]), 16, 0, 0);
        __builtin_amdgcn_global_load_lds(AS1(Br0 + kt), AS3(&Bt[(wave * 64) * 8]),       16, 0, 0);
        __builtin_amdgcn_global_load_lds(AS1(Br1 + kt), AS3(&Bt[(256 + wave * 64) * 8]), 16, 0, 0);
        __syncthreads();
        bf16x8 af[4], bff[4];
#pragma unroll
        for (int i = 0; i < 4; ++i) {
            af[i]  = *(const bf16x8*)&At[(wm * 64 + i * 16 + fr) * BK + fq * 8];
            bff[i] = *(const bf16x8*)&Bt[(wn * 64 + i * 16 + fr) * BK + fq * 8];
        }
#pragma unroll
        for (int i = 0; i < 4; ++i)
#pragma unroll
            for (int j = 0; j < 4; ++j)
                acc[i][j] = __builtin_amdgcn_mfma_f32_16x16x32_bf16(af[i], bff[j], acc[i][j], 0, 0, 0);
        __syncthreads();
    }

    const int cb = n0 + wn * 64 + fr;
#pragma unroll
    for (int mi = 0; mi < 4; ++mi) {
#pragma unroll
        for (int rr = 0; rr < 4; ++rr) {
            int r = mloc + wm * 64 + mi * 16 + fq * 4 + rr;
            float* prow = PREc + ((size_t)d * TCR + r) * G4;
#pragma unroll
            for (int ni = 0; ni < 4; ++ni) {
                int col = cb + ni * 16;
                prow[col] = acc[mi][ni][rr] + bp[d * G4 + col];
            }
        }
    }
}

// ---------------------------------------------------------------------------
// Persistent recurrence kernel, per-group barriers.
// Groups: (m-tile, d) -> 8 groups x 32 bx-blocks; each group is an independent
// recurrence (own h slice, own counter cacheline). Step layout:
//   h loads -> MFMA -> cell -> h stores -> vmcnt -> sync -> signal
//   -> out stores + PRE prefetch (overlap the poll) -> poll -> sync.
// ---------------------------------------------------------------------------
__global__ __launch_bounds__(256)
void lstm_chunk_kernel(const bf16_t* __restrict__ Whhp,  // (2,2048,512) bf16
                       const float* __restrict__ PREc,   // (2,TCR,2048)
                       const int* __restrict__ F_lens,
                       float* __restrict__ cfb,          // (2,256,512) f32
                       bf16_t* __restrict__ hbA,         // (2,256,512) bf16
                       bf16_t* __restrict__ hbB,         // (2,256,512) bf16
                       bf16_t* __restrict__ H1,          // (32768,1024) bf16 (mode 0)
                       float* __restrict__ OUT,          // (32768,1024) f32  (mode 1)
                       unsigned int* __restrict__ ctr,   // 8 group counters, 64B apart
                       int t0, int TC, int TCR, int mode, int s_base)
{
    const int d  = blockIdx.z;
    const int bx = blockIdx.x;          // unit group 0..31
    const int m0 = blockIdx.y * 64;
    const int tid = threadIdx.x;
    const int lane = tid & 63, wave = tid >> 6;
    const int fr = lane & 15, fq = lane >> 4;
    const int gslot = ((blockIdx.y << 1) | d) * 16;   // 64B-spaced counter

    __shared__ __attribute__((aligned(16))) bf16_t Bt[64 * 512];   // 64 KiB

    // Stage Whh slice (64 rows x 512 K) once; XOR-swizzled SOURCE, linear dest.
    const bf16_t* Bg = Whhp + ((size_t)d * G4 + bx * 64) * H_DIM;
#pragma unroll
    for (int it = 0; it < 16; ++it) {
        int c   = it * 256 + tid;
        int row = c >> 6, ck = c & 63;
        int cks = ck ^ (row & 7);
        __builtin_amdgcn_global_load_lds(AS1(Bg + (size_t)row * H_DIM + cks * 8),
                                         AS3(&Bt[(it * 256 + wave * 64) * 8]), 16, 0, 0);
    }

    // Per-lane constants (lane owns unit u for 4 fixed m-rows, all steps).
    const int mrow  = m0 + wave * 16 + fr;     // A-fragment row
    const int u     = bx * 16 + fr;
    const int cbcol = bx * 64 + fr;
    int mm[4], LL[4], sidx[4];
    float c_own[4], h_own[4];
    const float* pbase[4];
#pragma unroll
    for (int rr = 0; rr < 4; ++rr) {
        mm[rr]   = m0 + wave * 16 + fq * 4 + rr;
        LL[rr]   = F_lens[mm[rr]];
        sidx[rr] = (d * M_B + mm[rr]) * H_DIM + u;
        c_own[rr]= cfb[sidx[rr]];
        pbase[rr]= PREc + ((size_t)d * TCR + mm[rr]) * G4 + cbcol;
    }
    {
        const bf16_t* hin0 = (t0 & 1) ? hbB : hbA;
#pragma unroll
        for (int rr = 0; rr < 4; ++rr) h_own[rr] = (float)hin0[sidx[rr]];
    }

    // pv for step 0.
    float pv[4][4];
#pragma unroll
    for (int rr = 0; rr < 4; ++rr) {
#pragma unroll
        for (int g = 0; g < 4; ++g)
            pv[rr][g] = load_f32_async(pbase[rr] + g * 16);
    }

    __syncthreads();   // staging + pv drained (compiler emits vmcnt0 before barrier)

    for (int tt = 0; tt < TC; ++tt) {
        const int t = t0 + tt;
        const bf16_t* hin  = (t & 1) ? hbB : hbA;
        bf16_t*       hout = (t & 1) ? hbA : hbB;

        // h fragments (device-scope, bypass L1/L2 -> LLC where producers wrote).
        const bf16_t* Arow = hin + ((size_t)d * M_B + mrow) * H_DIM + fq * 8;
        bf16x8 af[16];
#pragma unroll
        for (int ks = 0; ks < 16; ++ks)
            af[ks] = load_h_dev(Arow + ks * 32);
        asm volatile("s_waitcnt vmcnt(0)" ::: "memory");
        __builtin_amdgcn_sched_barrier(0);

        f32x4 acc[4];
#pragma unroll
        for (int j = 0; j < 4; ++j) { f32x4 z = {0.f, 0.f, 0.f, 0.f}; acc[j] = z; }

#pragma unroll
        for (int ks = 0; ks < 16; ++ks) {
#pragma unroll
            for (int j = 0; j < 4; ++j) {
                int rb = j * 16 + fr;
                int ck = (ks * 4 + fq) ^ (rb & 7);
                bf16x8 bf = *(const bf16x8*)&Bt[rb * 512 + ck * 8];
                acc[j] = __builtin_amdgcn_mfma_f32_16x16x32_bf16(af[ks], bf, acc[j], 0, 0, 0);
            }
        }

        // LSTM cell + h stores (critical path).
#pragma unroll
        for (int rr = 0; rr < 4; ++rr) {
            bool mt = (t < LL[rr]);
            float gi = acc[0][rr] + pv[rr][0];
            float gf = acc[1][rr] + pv[rr][1];
            float gg = acc[2][rr] + pv[rr][2];
            float go = acc[3][rr] + pv[rr][3];
            float c2 = sigm(gf) * c_own[rr] + sigm(gi) * tanhfast(gg);
            float h2 = sigm(go) * tanhfast(c2);
            if (!mt) { c2 = c_own[rr]; h2 = h_own[rr]; }
            c_own[rr] = c2;
            h_own[rr] = h2;
            store_h_dev(&hout[sidx[rr]], (bf16_t)h2);
        }
        asm volatile("s_waitcnt vmcnt(0)" ::: "memory");  // h stores device-visible
        __syncthreads();
        if (tid == 0)
            __hip_atomic_fetch_add(&ctr[gslot], 1u, __ATOMIC_RELAXED, __HIP_MEMORY_SCOPE_AGENT);

        // Off-critical-path: output stores + next-step PRE prefetch (overlap poll).
#pragma unroll
        for (int rr = 0; rr < 4; ++rr) {
            bool mt = (t < LL[rr]);
            int trow = (d == 0 || !mt) ? t : (LL[rr] - 1 - t);
            size_t orow = (size_t)trow * M_B + mm[rr];
            if (mode == 0) H1[orow * 1024 + d * H_DIM + u] = (bf16_t)h_own[rr];
            else           OUT[orow * 1024 + d * H_DIM + u] = mt ? h_own[rr] : 0.f;
        }
        float pvn[4][4];
        if (tt + 1 < TC) {
#pragma unroll
            for (int rr = 0; rr < 4; ++rr) {
                const float* prow = pbase[rr] + (size_t)(tt + 1) * ((size_t)M_B * G4);
#pragma unroll
                for (int g = 0; g < 4; ++g)
                    pvn[rr][g] = load_f32_async(prow + g * 16);
            }
        }

        if (tid == 0) {
            unsigned int tgt = (unsigned int)(s_base + tt + 1) * 32u;
            while (__hip_atomic_load(&ctr[gslot], __ATOMIC_RELAXED, __HIP_MEMORY_SCOPE_AGENT) < tgt)
                __builtin_amdgcn_s_sleep(2);
        }
        __syncthreads();

        if (tt + 1 < TC) {
#pragma unroll
            for (int rr = 0; rr < 4; ++rr)
#pragma unroll
                for (int g = 0; g < 4; ++g)
                    pv[rr][g] = pvn[rr][g];
        }
    }

#pragma unroll
    for (int rr = 0; rr < 4; ++rr) cfb[sidx[rr]] = c_own[rr];
}

// ---------------------------------------------------------------------------
extern "C" void kernel_launch(void* const* d_in, const int* in_sizes, int n_in,
                              void* d_out, int out_size, void* d_ws, size_t ws_size,
                              hipStream_t stream)
{
    const int*   F      = (const int*)d_in[0];
    const int*   F_lens = (const int*)d_in[1];
    const float* emb    = (const float*)d_in[2];
    const float* Wih0   = (const float*)d_in[3];
    const float* Whh0   = (const float*)d_in[4];
    const float* b0     = (const float*)d_in[5];
    const float* Wih1   = (const float*)d_in[6];
    const float* Whh1   = (const float*)d_in[7];
    const float* b1     = (const float*)d_in[8];
    float* OUT = (float*)d_out;

    // Base workspace (~155 MiB), 256B-aligned blocks.
    char* p = (char*)d_ws;
    auto alloc = [&](size_t bytes) { char* q = p; p += (bytes + 255) & ~(size_t)255; return (void*)q; };
    bf16_t* X0    = (bf16_t*)alloc((size_t)N_ROWS * E_DIM * 2);   // 64 MiB
    bf16_t* H1    = (bf16_t*)alloc((size_t)N_ROWS * 1024 * 2);    // 64 MiB
    bf16_t* Wih0p = (bf16_t*)alloc((size_t)2 * G4 * E_DIM * 2);   // 8 MiB
    bf16_t* Whh0p = (bf16_t*)alloc((size_t)2 * G4 * H_DIM * 2);   // 4 MiB
    bf16_t* Wih1p = (bf16_t*)alloc((size_t)2 * G4 * E_DIM * 2);   // 8 MiB
    bf16_t* Whh1p = (bf16_t*)alloc((size_t)2 * G4 * H_DIM * 2);   // 4 MiB
    float*  b0p   = (float*)alloc((size_t)2 * G4 * 4);
    float*  b1p   = (float*)alloc((size_t)2 * G4 * 4);
    int*    srcrow= (int*)alloc((size_t)N_ROWS * 4);              // 128 KiB
    bf16_t* hbA   = (bf16_t*)alloc((size_t)2 * M_B * H_DIM * 2);
    bf16_t* hbB   = (bf16_t*)alloc((size_t)2 * M_B * H_DIM * 2);
    float*  cfb   = (float*)alloc((size_t)2 * M_B * H_DIM * 4);
    unsigned int* ctr = (unsigned int*)alloc(512);
    size_t base_used = (size_t)(p - (char*)d_ws);

    // Largest time-chunk whose f32 PRE buffer fits the remaining workspace.
    int TC = 0;
    const int tcs[8] = {128, 64, 32, 16, 8, 4, 2, 1};
    for (int i = 0; i < 8; ++i) {
        size_t need = base_used + (size_t)2 * tcs[i] * M_B * G4 * 4;
        if (need <= ws_size) { TC = tcs[i]; break; }
    }
    if (TC == 0) return;  // cannot run at all
    float* PREc = (float*)p;
    const int TCR = TC * M_B;

    hipMemsetAsync(ctr, 0, 512, stream);
    permute_weights_kernel<<<dim3(2 * G4), 256, 0, stream>>>(Wih0, Whh0, b0, Wih0p, Whh0p, b0p);
    permute_weights_kernel<<<dim3(2 * G4), 256, 0, stream>>>(Wih1, Whh1, b1, Wih1p, Whh1p, b1p);
    embed_kernel<<<dim3(N_ROWS), 256, 0, stream>>>(F, emb, X0);
    rowmap_kernel<<<dim3(N_ROWS / 256), 256, 0, stream>>>(F_lens, srcrow);

    for (int layer = 0; layer < 2; ++layer) {
        const bf16_t* Xin  = layer ? H1 : X0;
        const bf16_t* Wihp = layer ? Wih1p : Wih0p;
        const bf16_t* Whhp = layer ? Whh1p : Whh0p;
        const float*  bp   = layer ? b1p : b0p;

        hipMemsetAsync(hbA, 0, (size_t)2 * M_B * H_DIM * 2, stream);
        hipMemsetAsync(cfb, 0, (size_t)2 * M_B * H_DIM * 4, stream);

        for (int c = 0; c < S_LEN / TC; ++c) {
            gemm_pre_kernel<<<dim3(2 * (TCR / BM) * 16), 256, 0, stream>>>(
                Xin, Wihp, bp, srcrow, PREc, c * TCR, TCR);

            int t0v = c * TC, TCv = TC, TCRv = TCR, modev = layer;
            int s_basev = layer * S_LEN + c * TC;
            const bf16_t* Whhp_v = Whhp;
            const float*  PREc_v = PREc;
            const int*    Flen_v = F_lens;
            float*        cfb_v  = cfb;
            bf16_t*       hbA_v  = hbA;
            bf16_t*       hbB_v  = hbB;
            bf16_t*       H1_v   = H1;
            float*        OUT_v  = OUT;
            unsigned int* ctr_v  = ctr;
            void* kargs[14] = {
                (void*)&Whhp_v, (void*)&PREc_v, (void*)&Flen_v, (void*)&cfb_v,
                (void*)&hbA_v, (void*)&hbB_v, (void*)&H1_v, (void*)&OUT_v,
                (void*)&ctr_v, (void*)&t0v, (void*)&TCv, (void*)&TCRv,
                (void*)&modev, (void*)&s_basev
            };
            hipLaunchCooperativeKernel((void*)lstm_chunk_kernel,
                                       dim3(32, 4, 2), dim3(256, 1, 1),
                                       kargs, 0, stream);
        }
    }
}

// Round 6
// 2551.690 us; speedup vs baseline: 6.8379x; 1.0351x over previous
//
#include <hip/hip_runtime.h>
#include <hip/hip_bf16.h>

// Problem dims
#define S_LEN 128
#define M_B   256
#define E_DIM 1024
#define H_DIM 512
#define G4    2048          // 4*H
#define N_ROWS (S_LEN*M_B)  // 32768
#define KD    1024          // GEMM K for both layers (E = 2H = 1024)

typedef __bf16 bf16_t;
typedef __bf16 bf16x8 __attribute__((ext_vector_type(8)));
typedef float  f32x4  __attribute__((ext_vector_type(4)));
typedef int    i32x4  __attribute__((ext_vector_type(4)));

#define AS1(p) ((const __attribute__((address_space(1))) void*)(p))
#define AS3(p) ((__attribute__((address_space(3))) void*)(p))

__device__ __forceinline__ float sigm(float x)     { return 1.f / (1.f + __expf(-x)); }
__device__ __forceinline__ float tanhfast(float x) { return 2.f / (1.f + __expf(-2.f * x)) - 1.f; }

// Device-scope (LLC) h exchange: write-through stores, cache-bypassing loads.
__device__ __forceinline__ void store_h_dev(bf16_t* p, bf16_t v) {
    unsigned int w = (unsigned int)__builtin_bit_cast(unsigned short, v);
    asm volatile("global_store_short %0, %1, off sc0 sc1" :: "v"(p), "v"(w) : "memory");
}
__device__ __forceinline__ bf16x8 load_h_dev(const bf16_t* p) {
    i32x4 r;
    asm volatile("global_load_dwordx4 %0, %1, off sc0 sc1" : "=v"(r) : "v"(p) : "memory");
    return __builtin_bit_cast(bf16x8, r);
}
// Plain f32 load via asm: issues where written (not sunk to use point).
__device__ __forceinline__ float load_f32_async(const float* p) {
    float r;
    asm volatile("global_load_dword %0, %1, off" : "=v"(r) : "v"(p) : "memory");
    return r;
}

// ---------------------------------------------------------------------------
// Weight permutation + bf16 conversion.
// Gate permutation: j' = q*64 + gate*16 + u16  <->  j = gate*512 + (q*16+u16)
// ---------------------------------------------------------------------------
__global__ __launch_bounds__(256)
void permute_weights_kernel(const float* __restrict__ Wih, const float* __restrict__ Whh,
                            const float* __restrict__ b,
                            bf16_t* __restrict__ Wihp, bf16_t* __restrict__ Whhp,
                            float* __restrict__ bp)
{
    int bid = blockIdx.x;            // d*2048 + jp
    int d  = bid >> 11;
    int jp = bid & 2047;
    int q = jp >> 6, r = jp & 63;
    int gate = r >> 4, u16 = r & 15;
    int j = gate * H_DIM + q * 16 + u16;

    const float* s_ih = Wih + ((size_t)d * G4 + j) * E_DIM;
    bf16_t*      d_ih = Wihp + ((size_t)d * G4 + jp) * E_DIM;
    for (int e = threadIdx.x; e < E_DIM; e += 256) d_ih[e] = (bf16_t)s_ih[e];

    const float* s_hh = Whh + ((size_t)d * G4 + j) * H_DIM;
    bf16_t*      d_hh = Whhp + ((size_t)d * G4 + jp) * H_DIM;
    for (int k = threadIdx.x; k < H_DIM; k += 256) d_hh[k] = (bf16_t)s_hh[k];

    if (threadIdx.x == 0) bp[d * G4 + jp] = b[d * G4 + j];
}

// ---------------------------------------------------------------------------
// Embedding lookup -> bf16 X (32768 x 1024). emb[PAD_ID] is zero.
// ---------------------------------------------------------------------------
__global__ __launch_bounds__(256)
void embed_kernel(const int* __restrict__ F, const float* __restrict__ emb,
                  bf16_t* __restrict__ X)
{
    int n   = blockIdx.x;            // t*256 + m
    int tok = F[n];
    const float4* src = (const float4*)(emb + (size_t)tok * E_DIM);
    bf16_t*       dst = X + (size_t)n * E_DIM;
    for (int i = threadIdx.x; i < E_DIM / 4; i += 256) {
        float4 v = src[i];
        dst[i * 4 + 0] = (bf16_t)v.x;
        dst[i * 4 + 1] = (bf16_t)v.y;
        dst[i * 4 + 2] = (bf16_t)v.z;
        dst[i * 4 + 3] = (bf16_t)v.w;
    }
}

// ---------------------------------------------------------------------------
// srcrow[t*256+m] = ((t < L) ? L-1-t : t) * 256 + m   (self-inverse gather)
// ---------------------------------------------------------------------------
__global__ __launch_bounds__(256)
void rowmap_kernel(const int* __restrict__ F_lens, int* __restrict__ srcrow)
{
    int n = blockIdx.x * 256 + threadIdx.x;
    int t = n >> 8, m = n & 255;
    int L = F_lens[m];
    int st = (t < L) ? (L - 1 - t) : t;
    srcrow[n] = st * M_B + m;
}

// ---------------------------------------------------------------------------
// Chunked input-projection GEMM with XCD-chunked block swizzle.
// 1-D grid, nwg = 2 * (TCR/BM) * 16 (divisible by 8). Per-XCD contiguous wg
// range: 16 consecutive wg share one A-tile; B panel (4 MiB/dir) L2-resident.
// ---------------------------------------------------------------------------
#define BM 128
#define BN 128
#define BK 32

__global__ __launch_bounds__(256)
void gemm_pre_kernel(const bf16_t* __restrict__ A,    // (32768, 1024) bf16
                     const bf16_t* __restrict__ Wp,   // (2, 2048, 1024) bf16
                     const float* __restrict__ bp,    // (2, 2048)
                     const int* __restrict__ srcrow,  // (32768)
                     float* __restrict__ PREc,        // (2, TCR, 2048)
                     int rowbase, int TCR)
{
    // Bijective XCD-chunk swizzle (nwg % 8 == 0).
    const int nwg = gridDim.x;
    const int qx  = nwg >> 3;
    const int orig = blockIdx.x;
    const int wg   = (orig & 7) * qx + (orig >> 3);
    const int MT   = TCR / BM;
    const int n_t  = wg & 15;
    const int m_t  = (wg >> 4) % MT;
    const int d    = wg / (16 * MT);

    const int n0   = n_t * BN;
    const int mloc = m_t * BM;
    const int tid  = threadIdx.x;
    const int lane = tid & 63, wave = tid >> 6;
    const int wm = wave >> 1, wn = wave & 1;
    const int fr = lane & 15, fq = lane >> 4;

    __shared__ __attribute__((aligned(16))) bf16_t At[BM * BK];
    __shared__ __attribute__((aligned(16))) bf16_t Bt[BN * BK];

    const int r0 = tid >> 2;
    const int k8 = (tid & 3) * 8;
    const int n_0 = rowbase + mloc + r0;
    const int n_1 = n_0 + 64;
    const size_t srow0 = (d == 1) ? (size_t)srcrow[n_0] : (size_t)n_0;
    const size_t srow1 = (d == 1) ? (size_t)srcrow[n_1] : (size_t)n_1;
    const bf16_t* Ar0 = A + srow0 * KD + k8;
    const bf16_t* Ar1 = A + srow1 * KD + k8;
    const bf16_t* Br0 = Wp + ((size_t)d * G4 + n0 + r0) * KD + k8;
    const bf16_t* Br1 = Br0 + (size_t)64 * KD;

    f32x4 acc[4][4];
#pragma unroll
    for (int i = 0; i < 4; ++i)
#pragma unroll
        for (int j = 0; j < 4; ++j) { f32x4 z = {0.f, 0.f, 0.f, 0.f}; acc[i][j] = z; }

    for (int kt = 0; kt < KD; kt += BK) {
        __builtin_amdgcn_global_load_lds(AS1(Ar0 + kt), AS3(&At[(wave * 64) * 8]),       16, 0, 0);
        __builtin_amdgcn_global_load_lds(AS1(Ar1 + kt), AS3(&At[(256 + wave * 64) * 8]), 16, 0, 0);
        __builtin_amdgcn_global_load_lds(AS1(Br0 + kt), AS3(&Bt[(wave * 64) * 8]),       16, 0, 0);
        __builtin_amdgcn_global_load_lds(AS1(Br1 + kt), AS3(&Bt[(256 + wave * 64) * 8]), 16, 0, 0);
        __syncthreads();
        bf16x8 af[4], bff[4];
#pragma unroll
        for (int i = 0; i < 4; ++i) {
            af[i]  = *(const bf16x8*)&At[(wm * 64 + i * 16 + fr) * BK + fq * 8];
            bff[i] = *(const bf16x8*)&Bt[(wn * 64 + i * 16 + fr) * BK + fq * 8];
        }
#pragma unroll
        for (int i = 0; i < 4; ++i)
#pragma unroll
            for (int j = 0; j < 4; ++j)
                acc[i][j] = __builtin_amdgcn_mfma_f32_16x16x32_bf16(af[i], bff[j], acc[i][j], 0, 0, 0);
        __syncthreads();
    }

    const int cb = n0 + wn * 64 + fr;
#pragma unroll
    for (int mi = 0; mi < 4; ++mi) {
#pragma unroll
        for (int rr = 0; rr < 4; ++rr) {
            int r = mloc + wm * 64 + mi * 16 + fq * 4 + rr;
            float* prow = PREc + ((size_t)d * TCR + r) * G4;
#pragma unroll
            for (int ni = 0; ni < 4; ++ni) {
                int col = cb + ni * 16;
                prow[col] = acc[mi][ni][rr] + bp[d * G4 + col];
            }
        }
    }
}

// ---------------------------------------------------------------------------
// Persistent recurrence kernel, per-group barriers (PLAIN launch — the barrier
// is a hand-rolled atomic counter; no cooperative API needed. 256 blocks at
// 64KiB LDS / 96 VGPR all place immediately on an empty device).
// Groups: (m-tile, d) -> 8 groups x 32 bx-blocks; each group is an independent
// recurrence (own h slice, own counter cacheline). Step layout:
//   h loads -> MFMA -> cell -> h stores -> vmcnt -> sync -> signal
//   -> out stores + PRE prefetch (overlap the poll) -> poll -> sync.
// ---------------------------------------------------------------------------
__global__ __launch_bounds__(256)
void lstm_chunk_kernel(const bf16_t* __restrict__ Whhp,  // (2,2048,512) bf16
                       const float* __restrict__ PREc,   // (2,TCR,2048)
                       const int* __restrict__ F_lens,
                       float* __restrict__ cfb,          // (2,256,512) f32
                       bf16_t* __restrict__ hbA,         // (2,256,512) bf16
                       bf16_t* __restrict__ hbB,         // (2,256,512) bf16
                       bf16_t* __restrict__ H1,          // (32768,1024) bf16 (mode 0)
                       float* __restrict__ OUT,          // (32768,1024) f32  (mode 1)
                       unsigned int* __restrict__ ctr,   // 8 group counters, 64B apart
                       int t0, int TC, int TCR, int mode, int s_base)
{
    const int d  = blockIdx.z;
    const int bx = blockIdx.x;          // unit group 0..31
    const int m0 = blockIdx.y * 64;
    const int tid = threadIdx.x;
    const int lane = tid & 63, wave = tid >> 6;
    const int fr = lane & 15, fq = lane >> 4;
    const int gslot = ((blockIdx.y << 1) | d) * 16;   // 64B-spaced counter

    __shared__ __attribute__((aligned(16))) bf16_t Bt[64 * 512];   // 64 KiB

    // Stage Whh slice (64 rows x 512 K) once; XOR-swizzled SOURCE, linear dest.
    const bf16_t* Bg = Whhp + ((size_t)d * G4 + bx * 64) * H_DIM;
#pragma unroll
    for (int it = 0; it < 16; ++it) {
        int c   = it * 256 + tid;
        int row = c >> 6, ck = c & 63;
        int cks = ck ^ (row & 7);
        __builtin_amdgcn_global_load_lds(AS1(Bg + (size_t)row * H_DIM + cks * 8),
                                         AS3(&Bt[(it * 256 + wave * 64) * 8]), 16, 0, 0);
    }

    // Per-lane constants (lane owns unit u for 4 fixed m-rows, all steps).
    const int mrow  = m0 + wave * 16 + fr;     // A-fragment row
    const int u     = bx * 16 + fr;
    const int cbcol = bx * 64 + fr;
    int mm[4], LL[4], sidx[4];
    float c_own[4], h_own[4];
    const float* pbase[4];
#pragma unroll
    for (int rr = 0; rr < 4; ++rr) {
        mm[rr]   = m0 + wave * 16 + fq * 4 + rr;
        LL[rr]   = F_lens[mm[rr]];
        sidx[rr] = (d * M_B + mm[rr]) * H_DIM + u;
        c_own[rr]= cfb[sidx[rr]];
        pbase[rr]= PREc + ((size_t)d * TCR + mm[rr]) * G4 + cbcol;
    }
    {
        const bf16_t* hin0 = (t0 & 1) ? hbB : hbA;
#pragma unroll
        for (int rr = 0; rr < 4; ++rr) h_own[rr] = (float)hin0[sidx[rr]];
    }

    // pv for step 0.
    float pv[4][4];
#pragma unroll
    for (int rr = 0; rr < 4; ++rr) {
#pragma unroll
        for (int g = 0; g < 4; ++g)
            pv[rr][g] = load_f32_async(pbase[rr] + g * 16);
    }

    __syncthreads();   // staging + pv drained (compiler emits vmcnt0 before barrier)

    for (int tt = 0; tt < TC; ++tt) {
        const int t = t0 + tt;
        const bf16_t* hin  = (t & 1) ? hbB : hbA;
        bf16_t*       hout = (t & 1) ? hbA : hbB;

        // h fragments (device-scope, bypass L1/L2 -> LLC where producers wrote).
        const bf16_t* Arow = hin + ((size_t)d * M_B + mrow) * H_DIM + fq * 8;
        bf16x8 af[16];
#pragma unroll
        for (int ks = 0; ks < 16; ++ks)
            af[ks] = load_h_dev(Arow + ks * 32);
        asm volatile("s_waitcnt vmcnt(0)" ::: "memory");
        __builtin_amdgcn_sched_barrier(0);

        f32x4 acc[4];
#pragma unroll
        for (int j = 0; j < 4; ++j) { f32x4 z = {0.f, 0.f, 0.f, 0.f}; acc[j] = z; }

#pragma unroll
        for (int ks = 0; ks < 16; ++ks) {
#pragma unroll
            for (int j = 0; j < 4; ++j) {
                int rb = j * 16 + fr;
                int ck = (ks * 4 + fq) ^ (rb & 7);
                bf16x8 bf = *(const bf16x8*)&Bt[rb * 512 + ck * 8];
                acc[j] = __builtin_amdgcn_mfma_f32_16x16x32_bf16(af[ks], bf, acc[j], 0, 0, 0);
            }
        }

        // LSTM cell + h stores (critical path).
#pragma unroll
        for (int rr = 0; rr < 4; ++rr) {
            bool mt = (t < LL[rr]);
            float gi = acc[0][rr] + pv[rr][0];
            float gf = acc[1][rr] + pv[rr][1];
            float gg = acc[2][rr] + pv[rr][2];
            float go = acc[3][rr] + pv[rr][3];
            float c2 = sigm(gf) * c_own[rr] + sigm(gi) * tanhfast(gg);
            float h2 = sigm(go) * tanhfast(c2);
            if (!mt) { c2 = c_own[rr]; h2 = h_own[rr]; }
            c_own[rr] = c2;
            h_own[rr] = h2;
            store_h_dev(&hout[sidx[rr]], (bf16_t)h2);
        }
        asm volatile("s_waitcnt vmcnt(0)" ::: "memory");  // h stores device-visible
        __syncthreads();
        if (tid == 0)
            __hip_atomic_fetch_add(&ctr[gslot], 1u, __ATOMIC_RELAXED, __HIP_MEMORY_SCOPE_AGENT);

        // Off-critical-path: output stores + next-step PRE prefetch (overlap poll).
#pragma unroll
        for (int rr = 0; rr < 4; ++rr) {
            bool mt = (t < LL[rr]);
            int trow = (d == 0 || !mt) ? t : (LL[rr] - 1 - t);
            size_t orow = (size_t)trow * M_B + mm[rr];
            if (mode == 0) H1[orow * 1024 + d * H_DIM + u] = (bf16_t)h_own[rr];
            else           OUT[orow * 1024 + d * H_DIM + u] = mt ? h_own[rr] : 0.f;
        }
        float pvn[4][4];
        if (tt + 1 < TC) {
#pragma unroll
            for (int rr = 0; rr < 4; ++rr) {
                const float* prow = pbase[rr] + (size_t)(tt + 1) * ((size_t)M_B * G4);
#pragma unroll
                for (int g = 0; g < 4; ++g)
                    pvn[rr][g] = load_f32_async(prow + g * 16);
            }
        }

        if (tid == 0) {
            unsigned int tgt = (unsigned int)(s_base + tt + 1) * 32u;
            while (__hip_atomic_load(&ctr[gslot], __ATOMIC_RELAXED, __HIP_MEMORY_SCOPE_AGENT) < tgt)
                __builtin_amdgcn_s_sleep(2);
        }
        __syncthreads();

        if (tt + 1 < TC) {
#pragma unroll
            for (int rr = 0; rr < 4; ++rr)
#pragma unroll
                for (int g = 0; g < 4; ++g)
                    pv[rr][g] = pvn[rr][g];
        }
    }

#pragma unroll
    for (int rr = 0; rr < 4; ++rr) cfb[sidx[rr]] = c_own[rr];
}

// ---------------------------------------------------------------------------
extern "C" void kernel_launch(void* const* d_in, const int* in_sizes, int n_in,
                              void* d_out, int out_size, void* d_ws, size_t ws_size,
                              hipStream_t stream)
{
    const int*   F      = (const int*)d_in[0];
    const int*   F_lens = (const int*)d_in[1];
    const float* emb    = (const float*)d_in[2];
    const float* Wih0   = (const float*)d_in[3];
    const float* Whh0   = (const float*)d_in[4];
    const float* b0     = (const float*)d_in[5];
    const float* Wih1   = (const float*)d_in[6];
    const float* Whh1   = (const float*)d_in[7];
    const float* b1     = (const float*)d_in[8];
    float* OUT = (float*)d_out;

    // Base workspace (~155 MiB), 256B-aligned blocks.
    char* p = (char*)d_ws;
    auto alloc = [&](size_t bytes) { char* q = p; p += (bytes + 255) & ~(size_t)255; return (void*)q; };
    bf16_t* X0    = (bf16_t*)alloc((size_t)N_ROWS * E_DIM * 2);   // 64 MiB
    bf16_t* H1    = (bf16_t*)alloc((size_t)N_ROWS * 1024 * 2);    // 64 MiB
    bf16_t* Wih0p = (bf16_t*)alloc((size_t)2 * G4 * E_DIM * 2);   // 8 MiB
    bf16_t* Whh0p = (bf16_t*)alloc((size_t)2 * G4 * H_DIM * 2);   // 4 MiB
    bf16_t* Wih1p = (bf16_t*)alloc((size_t)2 * G4 * E_DIM * 2);   // 8 MiB
    bf16_t* Whh1p = (bf16_t*)alloc((size_t)2 * G4 * H_DIM * 2);   // 4 MiB
    float*  b0p   = (float*)alloc((size_t)2 * G4 * 4);
    float*  b1p   = (float*)alloc((size_t)2 * G4 * 4);
    int*    srcrow= (int*)alloc((size_t)N_ROWS * 4);              // 128 KiB
    bf16_t* hbA   = (bf16_t*)alloc((size_t)2 * M_B * H_DIM * 2);
    bf16_t* hbB   = (bf16_t*)alloc((size_t)2 * M_B * H_DIM * 2);
    float*  cfb   = (float*)alloc((size_t)2 * M_B * H_DIM * 4);
    unsigned int* ctr = (unsigned int*)alloc(512);
    size_t base_used = (size_t)(p - (char*)d_ws);

    // Largest time-chunk whose f32 PRE buffer fits the remaining workspace.
    int TC = 0;
    const int tcs[8] = {128, 64, 32, 16, 8, 4, 2, 1};
    for (int i = 0; i < 8; ++i) {
        size_t need = base_used + (size_t)2 * tcs[i] * M_B * G4 * 4;
        if (need <= ws_size) { TC = tcs[i]; break; }
    }
    if (TC == 0) return;  // cannot run at all
    float* PREc = (float*)p;
    const int TCR = TC * M_B;

    hipMemsetAsync(ctr, 0, 512, stream);
    permute_weights_kernel<<<dim3(2 * G4), 256, 0, stream>>>(Wih0, Whh0, b0, Wih0p, Whh0p, b0p);
    permute_weights_kernel<<<dim3(2 * G4), 256, 0, stream>>>(Wih1, Whh1, b1, Wih1p, Whh1p, b1p);
    embed_kernel<<<dim3(N_ROWS), 256, 0, stream>>>(F, emb, X0);
    rowmap_kernel<<<dim3(N_ROWS / 256), 256, 0, stream>>>(F_lens, srcrow);

    for (int layer = 0; layer < 2; ++layer) {
        const bf16_t* Xin  = layer ? H1 : X0;
        const bf16_t* Wihp = layer ? Wih1p : Wih0p;
        const bf16_t* Whhp = layer ? Whh1p : Whh0p;
        const float*  bp   = layer ? b1p : b0p;

        hipMemsetAsync(hbA, 0, (size_t)2 * M_B * H_DIM * 2, stream);
        hipMemsetAsync(cfb, 0, (size_t)2 * M_B * H_DIM * 4, stream);

        for (int c = 0; c < S_LEN / TC; ++c) {
            gemm_pre_kernel<<<dim3(2 * (TCR / BM) * 16), 256, 0, stream>>>(
                Xin, Wihp, bp, srcrow, PREc, c * TCR, TCR);

            lstm_chunk_kernel<<<dim3(32, 4, 2), dim3(256), 0, stream>>>(
                Whhp, PREc, F_lens, cfb, hbA, hbB, H1, OUT, ctr,
                c * TC, TC, TCR, layer, layer * S_LEN + c * TC);
        }
    }
}

// Round 8
// 2463.285 us; speedup vs baseline: 7.0833x; 1.0359x over previous
//
#include <hip/hip_runtime.h>
#include <hip/hip_bf16.h>

// Problem dims
#define S_LEN 128
#define M_B   256
#define E_DIM 1024
#define H_DIM 512
#define G4    2048          // 4*H
#define N_ROWS (S_LEN*M_B)  // 32768
#define KD    1024          // GEMM K for both layers (E = 2H = 1024)

typedef __bf16 bf16_t;
typedef __bf16 bf16x8 __attribute__((ext_vector_type(8)));
typedef float  f32x4  __attribute__((ext_vector_type(4)));
typedef int    i32x4  __attribute__((ext_vector_type(4)));

#define AS1(p) ((const __attribute__((address_space(1))) void*)(p))
#define AS3(p) ((__attribute__((address_space(3))) void*)(p))

__device__ __forceinline__ float sigm(float x)     { return 1.f / (1.f + __expf(-x)); }
__device__ __forceinline__ float tanhfast(float x) { return 2.f / (1.f + __expf(-2.f * x)) - 1.f; }

// Device-scope (LLC) h exchange: write-through stores, cache-bypassing loads.
__device__ __forceinline__ void store_h_dev(bf16_t* p, bf16_t v) {
    unsigned int w = (unsigned int)__builtin_bit_cast(unsigned short, v);
    asm volatile("global_store_short %0, %1, off sc0 sc1" :: "v"(p), "v"(w) : "memory");
}
__device__ __forceinline__ bf16x8 load_h_dev(const bf16_t* p) {
    i32x4 r;
    asm volatile("global_load_dwordx4 %0, %1, off sc0 sc1" : "=v"(r) : "v"(p) : "memory");
    return __builtin_bit_cast(bf16x8, r);
}
// Plain f32 load via asm: issues where written (not sunk to use point).
__device__ __forceinline__ float load_f32_async(const float* p) {
    float r;
    asm volatile("global_load_dword %0, %1, off" : "=v"(r) : "v"(p) : "memory");
    return r;
}

// ---------------------------------------------------------------------------
// Weight permutation + bf16 conversion, BOTH layers in one launch.
// Gate permutation: j' = q*64 + gate*16 + u16  <->  j = gate*512 + (q*16+u16)
// ---------------------------------------------------------------------------
__global__ __launch_bounds__(256)
void permute_all_kernel(const float* __restrict__ Wih0, const float* __restrict__ Whh0,
                        const float* __restrict__ b0,
                        const float* __restrict__ Wih1, const float* __restrict__ Whh1,
                        const float* __restrict__ b1,
                        bf16_t* __restrict__ Wih0p, bf16_t* __restrict__ Whh0p,
                        bf16_t* __restrict__ Wih1p, bf16_t* __restrict__ Whh1p,
                        float* __restrict__ b0p, float* __restrict__ b1p)
{
    int bid = blockIdx.x;            // lay*4096 + d*2048 + jp
    int lay = bid >> 12;
    int d   = (bid >> 11) & 1;
    int jp  = bid & 2047;
    int q = jp >> 6, r = jp & 63;
    int gate = r >> 4, u16 = r & 15;
    int j = gate * H_DIM + q * 16 + u16;

    const float* Wih = lay ? Wih1 : Wih0;
    const float* Whh = lay ? Whh1 : Whh0;
    const float* b   = lay ? b1 : b0;
    bf16_t* Wihp = lay ? Wih1p : Wih0p;
    bf16_t* Whhp = lay ? Whh1p : Whh0p;
    float*  bp   = lay ? b1p : b0p;

    const float* s_ih = Wih + ((size_t)d * G4 + j) * E_DIM;
    bf16_t*      d_ih = Wihp + ((size_t)d * G4 + jp) * E_DIM;
    for (int e = threadIdx.x; e < E_DIM; e += 256) d_ih[e] = (bf16_t)s_ih[e];

    const float* s_hh = Whh + ((size_t)d * G4 + j) * H_DIM;
    bf16_t*      d_hh = Whhp + ((size_t)d * G4 + jp) * H_DIM;
    for (int k = threadIdx.x; k < H_DIM; k += 256) d_hh[k] = (bf16_t)s_hh[k];

    if (threadIdx.x == 0) bp[d * G4 + jp] = b[d * G4 + j];
}

// ---------------------------------------------------------------------------
// Embedding lookup -> bf16 X (32768 x 1024), with rowmap fused (tid 0).
// srcrow[t*256+m] = ((t < L) ? L-1-t : t) * 256 + m   (self-inverse gather)
// ---------------------------------------------------------------------------
__global__ __launch_bounds__(256)
void embed_kernel(const int* __restrict__ F, const float* __restrict__ emb,
                  const int* __restrict__ F_lens,
                  bf16_t* __restrict__ X, int* __restrict__ srcrow)
{
    int n   = blockIdx.x;            // t*256 + m
    int tok = F[n];
    const float4* src = (const float4*)(emb + (size_t)tok * E_DIM);
    bf16_t*       dst = X + (size_t)n * E_DIM;
    for (int i = threadIdx.x; i < E_DIM / 4; i += 256) {
        float4 v = src[i];
        dst[i * 4 + 0] = (bf16_t)v.x;
        dst[i * 4 + 1] = (bf16_t)v.y;
        dst[i * 4 + 2] = (bf16_t)v.z;
        dst[i * 4 + 3] = (bf16_t)v.w;
    }
    if (threadIdx.x == 0) {
        int t = n >> 8, m = n & 255;
        int L = F_lens[m];
        int st = (t < L) ? (L - 1 - t) : t;
        srcrow[n] = st * M_B + m;
    }
}

// ---------------------------------------------------------------------------
// Chunked input-projection GEMM, BK=64, XOR-swizzled LDS (source-swizzled
// staging + swizzled ds_read: conflict-free), XCD-chunked block swizzle.
// ---------------------------------------------------------------------------
#define BM 128
#define BN 128
#define BKG 64

__global__ __launch_bounds__(256)
void gemm_pre_kernel(const bf16_t* __restrict__ A,    // (32768, 1024) bf16
                     const bf16_t* __restrict__ Wp,   // (2, 2048, 1024) bf16
                     const float* __restrict__ bp,    // (2, 2048)
                     const int* __restrict__ srcrow,  // (32768)
                     float* __restrict__ PREc,        // (2, TCR, 2048)
                     int rowbase, int TCR)
{
    // Bijective XCD-chunk swizzle (nwg % 8 == 0).
    const int nwg = gridDim.x;
    const int qx  = nwg >> 3;
    const int orig = blockIdx.x;
    const int wg   = (orig & 7) * qx + (orig >> 3);
    const int MT   = TCR / BM;
    const int n_t  = wg & 15;
    const int m_t  = (wg >> 4) % MT;
    const int d    = wg / (16 * MT);

    const int n0   = n_t * BN;
    const int mloc = m_t * BM;
    const int tid  = threadIdx.x;
    const int lane = tid & 63, wave = tid >> 6;
    const int wm = wave >> 1, wn = wave & 1;
    const int fr = lane & 15, fq = lane >> 4;

    __shared__ __attribute__((aligned(16))) bf16_t At[BM * BKG];   // 16 KiB
    __shared__ __attribute__((aligned(16))) bf16_t Bt[BN * BKG];   // 16 KiB

    // Staging: per thread 4 A-rows + 4 B-rows (rows rA + 32*it), fixed source
    // column-chunk co = swizzled by row (pre-swizzled source, linear dest).
    const int rA = tid >> 3;                           // 0..31
    const int co = (((tid & 7) ^ (rA & 7)) << 3);      // element offset in row
    size_t srowA[4];
    const bf16_t* Bp[4];
#pragma unroll
    for (int it = 0; it < 4; ++it) {
        int nn = rowbase + mloc + rA + it * 32;
        srowA[it] = (d == 1) ? (size_t)srcrow[nn] : (size_t)nn;
        Bp[it] = Wp + ((size_t)d * G4 + n0 + rA + it * 32) * KD + co;
    }

    f32x4 acc[4][4];
#pragma unroll
    for (int i = 0; i < 4; ++i)
#pragma unroll
        for (int j = 0; j < 4; ++j) { f32x4 z = {0.f, 0.f, 0.f, 0.f}; acc[i][j] = z; }

    for (int kt = 0; kt < KD; kt += BKG) {
#pragma unroll
        for (int it = 0; it < 4; ++it)
            __builtin_amdgcn_global_load_lds(AS1(A + srowA[it] * KD + kt + co),
                                             AS3(&At[(it * 256 + wave * 64) * 8]), 16, 0, 0);
#pragma unroll
        for (int it = 0; it < 4; ++it)
            __builtin_amdgcn_global_load_lds(AS1(Bp[it] + kt),
                                             AS3(&Bt[(it * 256 + wave * 64) * 8]), 16, 0, 0);
        __syncthreads();

        bf16x8 af[2][4], bff[2][4];
#pragma unroll
        for (int ks = 0; ks < 2; ++ks) {
#pragma unroll
            for (int i = 0; i < 4; ++i) {
                int ra = wm * 64 + i * 16 + fr;
                int ca = (ks * 4 + fq) ^ (ra & 7);
                af[ks][i] = *(const bf16x8*)&At[ra * BKG + ca * 8];
                int rb = wn * 64 + i * 16 + fr;
                int cbk = (ks * 4 + fq) ^ (rb & 7);
                bff[ks][i] = *(const bf16x8*)&Bt[rb * BKG + cbk * 8];
            }
        }
#pragma unroll
        for (int ks = 0; ks < 2; ++ks)
#pragma unroll
            for (int i = 0; i < 4; ++i)
#pragma unroll
                for (int j = 0; j < 4; ++j)
                    acc[i][j] = __builtin_amdgcn_mfma_f32_16x16x32_bf16(af[ks][i], bff[ks][j], acc[i][j], 0, 0, 0);
        __syncthreads();
    }

    const int cb = n0 + wn * 64 + fr;
#pragma unroll
    for (int mi = 0; mi < 4; ++mi) {
#pragma unroll
        for (int rr = 0; rr < 4; ++rr) {
            int r = mloc + wm * 64 + mi * 16 + fq * 4 + rr;
            float* prow = PREc + ((size_t)d * TCR + r) * G4;
#pragma unroll
            for (int ni = 0; ni < 4; ++ni) {
                int col = cb + ni * 16;
                prow[col] = acc[mi][ni][rr] + bp[d * G4 + col];
            }
        }
    }
}

// ---------------------------------------------------------------------------
// Persistent recurrence kernel, per-group barriers — EXACT round-6 version
// (proven correct at absmax 2.44e-4). Grid (32,4,2)=256 blocks, 64KiB LDS.
// Groups: (my,d) -> 8 groups x 32 blocks, own counter cacheline.
// ---------------------------------------------------------------------------
__global__ __launch_bounds__(256)
void lstm_chunk_kernel(const bf16_t* __restrict__ Whhp,  // (2,2048,512) bf16
                       const float* __restrict__ PREc,   // (2,TCR,2048)
                       const int* __restrict__ F_lens,
                       float* __restrict__ cfb,          // (2,256,512) f32
                       bf16_t* __restrict__ hbA,         // (2,256,512) bf16
                       bf16_t* __restrict__ hbB,         // (2,256,512) bf16
                       bf16_t* __restrict__ H1,          // (32768,1024) bf16 (mode 0)
                       float* __restrict__ OUT,          // (32768,1024) f32  (mode 1)
                       unsigned int* __restrict__ ctr,   // 8 group counters, 64B apart
                       int t0, int TC, int TCR, int mode, int s_base)
{
    const int d  = blockIdx.z;
    const int bx = blockIdx.x;          // unit group 0..31
    const int m0 = blockIdx.y * 64;
    const int tid = threadIdx.x;
    const int lane = tid & 63, wave = tid >> 6;
    const int fr = lane & 15, fq = lane >> 4;
    const int gslot = ((blockIdx.y << 1) | d) * 16;   // 64B-spaced counter

    __shared__ __attribute__((aligned(16))) bf16_t Bt[64 * 512];   // 64 KiB

    // Stage Whh slice (64 rows x 512 K) once; XOR-swizzled SOURCE, linear dest.
    const bf16_t* Bg = Whhp + ((size_t)d * G4 + bx * 64) * H_DIM;
#pragma unroll
    for (int it = 0; it < 16; ++it) {
        int c   = it * 256 + tid;
        int row = c >> 6, ck = c & 63;
        int cks = ck ^ (row & 7);
        __builtin_amdgcn_global_load_lds(AS1(Bg + (size_t)row * H_DIM + cks * 8),
                                         AS3(&Bt[(it * 256 + wave * 64) * 8]), 16, 0, 0);
    }

    // Per-lane constants (lane owns unit u for 4 fixed m-rows, all steps).
    const int mrow  = m0 + wave * 16 + fr;     // A-fragment row
    const int u     = bx * 16 + fr;
    const int cbcol = bx * 64 + fr;
    int mm[4], LL[4], sidx[4];
    float c_own[4], h_own[4];
    const float* pbase[4];
#pragma unroll
    for (int rr = 0; rr < 4; ++rr) {
        mm[rr]   = m0 + wave * 16 + fq * 4 + rr;
        LL[rr]   = F_lens[mm[rr]];
        sidx[rr] = (d * M_B + mm[rr]) * H_DIM + u;
        c_own[rr]= cfb[sidx[rr]];
        pbase[rr]= PREc + ((size_t)d * TCR + mm[rr]) * G4 + cbcol;
    }
    {
        const bf16_t* hin0 = (t0 & 1) ? hbB : hbA;
#pragma unroll
        for (int rr = 0; rr < 4; ++rr) h_own[rr] = (float)hin0[sidx[rr]];
    }

    // pv for step 0.
    float pv[4][4];
#pragma unroll
    for (int rr = 0; rr < 4; ++rr) {
#pragma unroll
        for (int g = 0; g < 4; ++g)
            pv[rr][g] = load_f32_async(pbase[rr] + g * 16);
    }

    __syncthreads();   // staging + pv drained (compiler emits vmcnt0 before barrier)

    for (int tt = 0; tt < TC; ++tt) {
        const int t = t0 + tt;
        const bf16_t* hin  = (t & 1) ? hbB : hbA;
        bf16_t*       hout = (t & 1) ? hbA : hbB;

        // h fragments (device-scope, bypass L1/L2 -> LLC where producers wrote).
        const bf16_t* Arow = hin + ((size_t)d * M_B + mrow) * H_DIM + fq * 8;
        bf16x8 af[16];
#pragma unroll
        for (int ks = 0; ks < 16; ++ks)
            af[ks] = load_h_dev(Arow + ks * 32);
        asm volatile("s_waitcnt vmcnt(0)" ::: "memory");
        __builtin_amdgcn_sched_barrier(0);

        f32x4 acc[4];
#pragma unroll
        for (int j = 0; j < 4; ++j) { f32x4 z = {0.f, 0.f, 0.f, 0.f}; acc[j] = z; }

#pragma unroll
        for (int ks = 0; ks < 16; ++ks) {
#pragma unroll
            for (int j = 0; j < 4; ++j) {
                int rb = j * 16 + fr;
                int ck = (ks * 4 + fq) ^ (rb & 7);
                bf16x8 bf = *(const bf16x8*)&Bt[rb * 512 + ck * 8];
                acc[j] = __builtin_amdgcn_mfma_f32_16x16x32_bf16(af[ks], bf, acc[j], 0, 0, 0);
            }
        }

        // LSTM cell + h stores (critical path).
#pragma unroll
        for (int rr = 0; rr < 4; ++rr) {
            bool mt = (t < LL[rr]);
            float gi = acc[0][rr] + pv[rr][0];
            float gf = acc[1][rr] + pv[rr][1];
            float gg = acc[2][rr] + pv[rr][2];
            float go = acc[3][rr] + pv[rr][3];
            float c2 = sigm(gf) * c_own[rr] + sigm(gi) * tanhfast(gg);
            float h2 = sigm(go) * tanhfast(c2);
            if (!mt) { c2 = c_own[rr]; h2 = h_own[rr]; }
            c_own[rr] = c2;
            h_own[rr] = h2;
            store_h_dev(&hout[sidx[rr]], (bf16_t)h2);
        }
        asm volatile("s_waitcnt vmcnt(0)" ::: "memory");  // h stores device-visible
        __syncthreads();
        if (tid == 0)
            __hip_atomic_fetch_add(&ctr[gslot], 1u, __ATOMIC_RELAXED, __HIP_MEMORY_SCOPE_AGENT);

        // Off-critical-path: output stores + next-step PRE prefetch (overlap poll).
#pragma unroll
        for (int rr = 0; rr < 4; ++rr) {
            bool mt = (t < LL[rr]);
            int trow = (d == 0 || !mt) ? t : (LL[rr] - 1 - t);
            size_t orow = (size_t)trow * M_B + mm[rr];
            if (mode == 0) H1[orow * 1024 + d * H_DIM + u] = (bf16_t)h_own[rr];
            else           OUT[orow * 1024 + d * H_DIM + u] = mt ? h_own[rr] : 0.f;
        }
        float pvn[4][4];
        if (tt + 1 < TC) {
#pragma unroll
            for (int rr = 0; rr < 4; ++rr) {
                const float* prow = pbase[rr] + (size_t)(tt + 1) * ((size_t)M_B * G4);
#pragma unroll
                for (int g = 0; g < 4; ++g)
                    pvn[rr][g] = load_f32_async(prow + g * 16);
            }
        }

        if (tid == 0) {
            unsigned int tgt = (unsigned int)(s_base + tt + 1) * 32u;
            while (__hip_atomic_load(&ctr[gslot], __ATOMIC_RELAXED, __HIP_MEMORY_SCOPE_AGENT) < tgt)
                __builtin_amdgcn_s_sleep(2);
        }
        __syncthreads();

        if (tt + 1 < TC) {
#pragma unroll
            for (int rr = 0; rr < 4; ++rr)
#pragma unroll
                for (int g = 0; g < 4; ++g)
                    pv[rr][g] = pvn[rr][g];
        }
    }

#pragma unroll
    for (int rr = 0; rr < 4; ++rr) cfb[sidx[rr]] = c_own[rr];
}

// ---------------------------------------------------------------------------
extern "C" void kernel_launch(void* const* d_in, const int* in_sizes, int n_in,
                              void* d_out, int out_size, void* d_ws, size_t ws_size,
                              hipStream_t stream)
{
    const int*   F      = (const int*)d_in[0];
    const int*   F_lens = (const int*)d_in[1];
    const float* emb    = (const float*)d_in[2];
    const float* Wih0   = (const float*)d_in[3];
    const float* Whh0   = (const float*)d_in[4];
    const float* b0     = (const float*)d_in[5];
    const float* Wih1   = (const float*)d_in[6];
    const float* Whh1   = (const float*)d_in[7];
    const float* b1     = (const float*)d_in[8];
    float* OUT = (float*)d_out;

    // Base workspace (~155 MiB), 256B-aligned blocks.
    char* p = (char*)d_ws;
    auto alloc = [&](size_t bytes) { char* q = p; p += (bytes + 255) & ~(size_t)255; return (void*)q; };
    bf16_t* X0    = (bf16_t*)alloc((size_t)N_ROWS * E_DIM * 2);   // 64 MiB
    bf16_t* H1    = (bf16_t*)alloc((size_t)N_ROWS * 1024 * 2);    // 64 MiB
    bf16_t* Wih0p = (bf16_t*)alloc((size_t)2 * G4 * E_DIM * 2);   // 8 MiB
    bf16_t* Whh0p = (bf16_t*)alloc((size_t)2 * G4 * H_DIM * 2);   // 4 MiB
    bf16_t* Wih1p = (bf16_t*)alloc((size_t)2 * G4 * E_DIM * 2);   // 8 MiB
    bf16_t* Whh1p = (bf16_t*)alloc((size_t)2 * G4 * H_DIM * 2);   // 4 MiB
    float*  b0p   = (float*)alloc((size_t)2 * G4 * 4);
    float*  b1p   = (float*)alloc((size_t)2 * G4 * 4);
    int*    srcrow= (int*)alloc((size_t)N_ROWS * 4);              // 128 KiB
    bf16_t* hbA   = (bf16_t*)alloc((size_t)2 * M_B * H_DIM * 2);
    bf16_t* hbB   = (bf16_t*)alloc((size_t)2 * M_B * H_DIM * 2);
    float*  cfb   = (float*)alloc((size_t)2 * M_B * H_DIM * 4);
    unsigned int* ctr = (unsigned int*)alloc(512);
    size_t base_used = (size_t)(p - (char*)d_ws);

    // Largest time-chunk whose f32 PRE buffer fits the remaining workspace.
    int TC = 0;
    const int tcs[8] = {128, 64, 32, 16, 8, 4, 2, 1};
    for (int i = 0; i < 8; ++i) {
        size_t need = base_used + (size_t)2 * tcs[i] * M_B * G4 * 4;
        if (need <= ws_size) { TC = tcs[i]; break; }
    }
    if (TC == 0) return;  // cannot run at all
    float* PREc = (float*)p;
    const int TCR = TC * M_B;

    hipMemsetAsync(ctr, 0, 512, stream);
    permute_all_kernel<<<dim3(2 * 2 * G4), 256, 0, stream>>>(
        Wih0, Whh0, b0, Wih1, Whh1, b1, Wih0p, Whh0p, Wih1p, Whh1p, b0p, b1p);
    embed_kernel<<<dim3(N_ROWS), 256, 0, stream>>>(F, emb, F_lens, X0, srcrow);

    for (int layer = 0; layer < 2; ++layer) {
        const bf16_t* Xin  = layer ? H1 : X0;
        const bf16_t* Wihp = layer ? Wih1p : Wih0p;
        const bf16_t* Whhp = layer ? Whh1p : Whh0p;
        const float*  bp   = layer ? b1p : b0p;

        hipMemsetAsync(hbA, 0, (size_t)2 * M_B * H_DIM * 2, stream);
        hipMemsetAsync(cfb, 0, (size_t)2 * M_B * H_DIM * 4, stream);

        for (int c = 0; c < S_LEN / TC; ++c) {
            gemm_pre_kernel<<<dim3(2 * (TCR / BM) * 16), 256, 0, stream>>>(
                Xin, Wihp, bp, srcrow, PREc, c * TCR, TCR);

            lstm_chunk_kernel<<<dim3(32, 4, 2), dim3(256), 0, stream>>>(
                Whhp, PREc, F_lens, cfb, hbA, hbB, H1, OUT, ctr,
                c * TC, TC, TCR, layer, layer * S_LEN + c * TC);
        }
    }
}

// Round 9
// 2417.661 us; speedup vs baseline: 7.2170x; 1.0189x over previous
//
#include <hip/hip_runtime.h>
#include <hip/hip_bf16.h>

// Problem dims
#define S_LEN 128
#define M_B   256
#define E_DIM 1024
#define H_DIM 512
#define G4    2048          // 4*H
#define N_ROWS (S_LEN*M_B)  // 32768
#define KD    1024          // GEMM K for both layers (E = 2H = 1024)

typedef __bf16 bf16_t;
typedef __bf16 bf16x8 __attribute__((ext_vector_type(8)));
typedef float  f32x4  __attribute__((ext_vector_type(4)));
typedef int    i32x4  __attribute__((ext_vector_type(4)));

#define AS1(p) ((const __attribute__((address_space(1))) void*)(p))
#define AS3(p) ((__attribute__((address_space(3))) void*)(p))

__device__ __forceinline__ float sigm(float x)     { return 1.f / (1.f + __expf(-x)); }
__device__ __forceinline__ float tanhfast(float x) { return 2.f / (1.f + __expf(-2.f * x)) - 1.f; }

// Device-scope (LLC) h exchange: write-through stores, cache-bypassing loads.
__device__ __forceinline__ void store_h_dev(bf16_t* p, bf16_t v) {
    unsigned int w = (unsigned int)__builtin_bit_cast(unsigned short, v);
    asm volatile("global_store_short %0, %1, off sc0 sc1" :: "v"(p), "v"(w) : "memory");
}
__device__ __forceinline__ bf16x8 load_h_dev(const bf16_t* p) {
    i32x4 r;
    asm volatile("global_load_dwordx4 %0, %1, off sc0 sc1" : "=v"(r) : "v"(p) : "memory");
    return __builtin_bit_cast(bf16x8, r);
}
// Plain f32 load via asm: issues where written (not sunk to use point).
__device__ __forceinline__ float load_f32_async(const float* p) {
    float r;
    asm volatile("global_load_dword %0, %1, off" : "=v"(r) : "v"(p) : "memory");
    return r;
}

// ---------------------------------------------------------------------------
// Weight permutation + bf16 conversion, BOTH layers in one launch.
// Gate permutation: j' = q*64 + gate*16 + u16  <->  j = gate*512 + (q*16+u16)
// ---------------------------------------------------------------------------
__global__ __launch_bounds__(256)
void permute_all_kernel(const float* __restrict__ Wih0, const float* __restrict__ Whh0,
                        const float* __restrict__ b0,
                        const float* __restrict__ Wih1, const float* __restrict__ Whh1,
                        const float* __restrict__ b1,
                        bf16_t* __restrict__ Wih0p, bf16_t* __restrict__ Whh0p,
                        bf16_t* __restrict__ Wih1p, bf16_t* __restrict__ Whh1p,
                        float* __restrict__ b0p, float* __restrict__ b1p)
{
    int bid = blockIdx.x;            // lay*4096 + d*2048 + jp
    int lay = bid >> 12;
    int d   = (bid >> 11) & 1;
    int jp  = bid & 2047;
    int q = jp >> 6, r = jp & 63;
    int gate = r >> 4, u16 = r & 15;
    int j = gate * H_DIM + q * 16 + u16;

    const float* Wih = lay ? Wih1 : Wih0;
    const float* Whh = lay ? Whh1 : Whh0;
    const float* b   = lay ? b1 : b0;
    bf16_t* Wihp = lay ? Wih1p : Wih0p;
    bf16_t* Whhp = lay ? Whh1p : Whh0p;
    float*  bp   = lay ? b1p : b0p;

    const float* s_ih = Wih + ((size_t)d * G4 + j) * E_DIM;
    bf16_t*      d_ih = Wihp + ((size_t)d * G4 + jp) * E_DIM;
    for (int e = threadIdx.x; e < E_DIM; e += 256) d_ih[e] = (bf16_t)s_ih[e];

    const float* s_hh = Whh + ((size_t)d * G4 + j) * H_DIM;
    bf16_t*      d_hh = Whhp + ((size_t)d * G4 + jp) * H_DIM;
    for (int k = threadIdx.x; k < H_DIM; k += 256) d_hh[k] = (bf16_t)s_hh[k];

    if (threadIdx.x == 0) bp[d * G4 + jp] = b[d * G4 + j];
}

// ---------------------------------------------------------------------------
// Embedding lookup -> bf16 X (32768 x 1024), with rowmap fused (tid 0).
// srcrow[t*256+m] = ((t < L) ? L-1-t : t) * 256 + m   (self-inverse gather)
// ---------------------------------------------------------------------------
__global__ __launch_bounds__(256)
void embed_kernel(const int* __restrict__ F, const float* __restrict__ emb,
                  const int* __restrict__ F_lens,
                  bf16_t* __restrict__ X, int* __restrict__ srcrow)
{
    int n   = blockIdx.x;            // t*256 + m
    int tok = F[n];
    const float4* src = (const float4*)(emb + (size_t)tok * E_DIM);
    bf16_t*       dst = X + (size_t)n * E_DIM;
    for (int i = threadIdx.x; i < E_DIM / 4; i += 256) {
        float4 v = src[i];
        dst[i * 4 + 0] = (bf16_t)v.x;
        dst[i * 4 + 1] = (bf16_t)v.y;
        dst[i * 4 + 2] = (bf16_t)v.z;
        dst[i * 4 + 3] = (bf16_t)v.w;
    }
    if (threadIdx.x == 0) {
        int t = n >> 8, m = n & 255;
        int L = F_lens[m];
        int st = (t < L) ? (L - 1 - t) : t;
        srcrow[n] = st * M_B + m;
    }
}

// ---------------------------------------------------------------------------
// Chunked input-projection GEMM, BK=64, XOR-swizzled LDS (source-swizzled
// staging + swizzled ds_read: conflict-free), XCD-chunked block swizzle.
// ---------------------------------------------------------------------------
#define BM 128
#define BN 128
#define BKG 64

__global__ __launch_bounds__(256)
void gemm_pre_kernel(const bf16_t* __restrict__ A,    // (32768, 1024) bf16
                     const bf16_t* __restrict__ Wp,   // (2, 2048, 1024) bf16
                     const float* __restrict__ bp,    // (2, 2048)
                     const int* __restrict__ srcrow,  // (32768)
                     float* __restrict__ PREc,        // (2, TCR, 2048)
                     int rowbase, int TCR)
{
    // Bijective XCD-chunk swizzle (nwg % 8 == 0).
    const int nwg = gridDim.x;
    const int qx  = nwg >> 3;
    const int orig = blockIdx.x;
    const int wg   = (orig & 7) * qx + (orig >> 3);
    const int MT   = TCR / BM;
    const int n_t  = wg & 15;
    const int m_t  = (wg >> 4) % MT;
    const int d    = wg / (16 * MT);

    const int n0   = n_t * BN;
    const int mloc = m_t * BM;
    const int tid  = threadIdx.x;
    const int lane = tid & 63, wave = tid >> 6;
    const int wm = wave >> 1, wn = wave & 1;
    const int fr = lane & 15, fq = lane >> 4;

    __shared__ __attribute__((aligned(16))) bf16_t At[BM * BKG];   // 16 KiB
    __shared__ __attribute__((aligned(16))) bf16_t Bt[BN * BKG];   // 16 KiB

    // Staging: per thread 4 A-rows + 4 B-rows (rows rA + 32*it), fixed source
    // column-chunk co = swizzled by row (pre-swizzled source, linear dest).
    const int rA = tid >> 3;                           // 0..31
    const int co = (((tid & 7) ^ (rA & 7)) << 3);      // element offset in row
    size_t srowA[4];
    const bf16_t* Bp[4];
#pragma unroll
    for (int it = 0; it < 4; ++it) {
        int nn = rowbase + mloc + rA + it * 32;
        srowA[it] = (d == 1) ? (size_t)srcrow[nn] : (size_t)nn;
        Bp[it] = Wp + ((size_t)d * G4 + n0 + rA + it * 32) * KD + co;
    }

    f32x4 acc[4][4];
#pragma unroll
    for (int i = 0; i < 4; ++i)
#pragma unroll
        for (int j = 0; j < 4; ++j) { f32x4 z = {0.f, 0.f, 0.f, 0.f}; acc[i][j] = z; }

    for (int kt = 0; kt < KD; kt += BKG) {
#pragma unroll
        for (int it = 0; it < 4; ++it)
            __builtin_amdgcn_global_load_lds(AS1(A + srowA[it] * KD + kt + co),
                                             AS3(&At[(it * 256 + wave * 64) * 8]), 16, 0, 0);
#pragma unroll
        for (int it = 0; it < 4; ++it)
            __builtin_amdgcn_global_load_lds(AS1(Bp[it] + kt),
                                             AS3(&Bt[(it * 256 + wave * 64) * 8]), 16, 0, 0);
        __syncthreads();

        bf16x8 af[2][4], bff[2][4];
#pragma unroll
        for (int ks = 0; ks < 2; ++ks) {
#pragma unroll
            for (int i = 0; i < 4; ++i) {
                int ra = wm * 64 + i * 16 + fr;
                int ca = (ks * 4 + fq) ^ (ra & 7);
                af[ks][i] = *(const bf16x8*)&At[ra * BKG + ca * 8];
                int rb = wn * 64 + i * 16 + fr;
                int cbk = (ks * 4 + fq) ^ (rb & 7);
                bff[ks][i] = *(const bf16x8*)&Bt[rb * BKG + cbk * 8];
            }
        }
#pragma unroll
        for (int ks = 0; ks < 2; ++ks)
#pragma unroll
            for (int i = 0; i < 4; ++i)
#pragma unroll
                for (int j = 0; j < 4; ++j)
                    acc[i][j] = __builtin_amdgcn_mfma_f32_16x16x32_bf16(af[ks][i], bff[ks][j], acc[i][j], 0, 0, 0);
        __syncthreads();
    }

    const int cb = n0 + wn * 64 + fr;
#pragma unroll
    for (int mi = 0; mi < 4; ++mi) {
#pragma unroll
        for (int rr = 0; rr < 4; ++rr) {
            int r = mloc + wm * 64 + mi * 16 + fq * 4 + rr;
            float* prow = PREc + ((size_t)d * TCR + r) * G4;
#pragma unroll
            for (int ni = 0; ni < 4; ++ni) {
                int col = cb + ni * 16;
                prow[col] = acc[mi][ni][rr] + bp[d * G4 + col];
            }
        }
    }
}

// ---------------------------------------------------------------------------
// Persistent recurrence kernel, per-group barriers — EXACT round-6 version
// (proven correct at absmax 2.44e-4). Grid (32,4,2)=256 blocks, 64KiB LDS.
// Groups: (my,d) -> 8 groups x 32 blocks, own counter cacheline.
// ---------------------------------------------------------------------------
__global__ __launch_bounds__(256)
void lstm_chunk_kernel(const bf16_t* __restrict__ Whhp,  // (2,2048,512) bf16
                       const float* __restrict__ PREc,   // (2,TCR,2048)
                       const int* __restrict__ F_lens,
                       float* __restrict__ cfb,          // (2,256,512) f32
                       bf16_t* __restrict__ hbA,         // (2,256,512) bf16
                       bf16_t* __restrict__ hbB,         // (2,256,512) bf16
                       bf16_t* __restrict__ H1,          // (32768,1024) bf16 (mode 0)
                       float* __restrict__ OUT,          // (32768,1024) f32  (mode 1)
                       unsigned int* __restrict__ ctr,   // 8 group counters, 64B apart
                       int t0, int TC, int TCR, int mode, int s_base)
{
    const int d  = blockIdx.z;
    const int bx = blockIdx.x;          // unit group 0..31
    const int m0 = blockIdx.y * 64;
    const int tid = threadIdx.x;
    const int lane = tid & 63, wave = tid >> 6;
    const int fr = lane & 15, fq = lane >> 4;
    const int gslot = ((blockIdx.y << 1) | d) * 16;   // 64B-spaced counter

    __shared__ __attribute__((aligned(16))) bf16_t Bt[64 * 512];   // 64 KiB

    // Stage Whh slice (64 rows x 512 K) once; XOR-swizzled SOURCE, linear dest.
    const bf16_t* Bg = Whhp + ((size_t)d * G4 + bx * 64) * H_DIM;
#pragma unroll
    for (int it = 0; it < 16; ++it) {
        int c   = it * 256 + tid;
        int row = c >> 6, ck = c & 63;
        int cks = ck ^ (row & 7);
        __builtin_amdgcn_global_load_lds(AS1(Bg + (size_t)row * H_DIM + cks * 8),
                                         AS3(&Bt[(it * 256 + wave * 64) * 8]), 16, 0, 0);
    }

    // Per-lane constants (lane owns unit u for 4 fixed m-rows, all steps).
    const int mrow  = m0 + wave * 16 + fr;     // A-fragment row
    const int u     = bx * 16 + fr;
    const int cbcol = bx * 64 + fr;
    int mm[4], LL[4], sidx[4];
    float c_own[4], h_own[4];
    const float* pbase[4];
#pragma unroll
    for (int rr = 0; rr < 4; ++rr) {
        mm[rr]   = m0 + wave * 16 + fq * 4 + rr;
        LL[rr]   = F_lens[mm[rr]];
        sidx[rr] = (d * M_B + mm[rr]) * H_DIM + u;
        c_own[rr]= cfb[sidx[rr]];
        pbase[rr]= PREc + ((size_t)d * TCR + mm[rr]) * G4 + cbcol;
    }
    {
        const bf16_t* hin0 = (t0 & 1) ? hbB : hbA;
#pragma unroll
        for (int rr = 0; rr < 4; ++rr) h_own[rr] = (float)hin0[sidx[rr]];
    }

    // pv for step 0.
    float pv[4][4];
#pragma unroll
    for (int rr = 0; rr < 4; ++rr) {
#pragma unroll
        for (int g = 0; g < 4; ++g)
            pv[rr][g] = load_f32_async(pbase[rr] + g * 16);
    }

    __syncthreads();   // staging + pv drained (compiler emits vmcnt0 before barrier)

    for (int tt = 0; tt < TC; ++tt) {
        const int t = t0 + tt;
        const bf16_t* hin  = (t & 1) ? hbB : hbA;
        bf16_t*       hout = (t & 1) ? hbA : hbB;

        // h fragments (device-scope, bypass L1/L2 -> LLC where producers wrote).
        const bf16_t* Arow = hin + ((size_t)d * M_B + mrow) * H_DIM + fq * 8;
        bf16x8 af[16];
#pragma unroll
        for (int ks = 0; ks < 16; ++ks)
            af[ks] = load_h_dev(Arow + ks * 32);
        asm volatile("s_waitcnt vmcnt(0)" ::: "memory");
        __builtin_amdgcn_sched_barrier(0);

        f32x4 acc[4];
#pragma unroll
        for (int j = 0; j < 4; ++j) { f32x4 z = {0.f, 0.f, 0.f, 0.f}; acc[j] = z; }

#pragma unroll
        for (int ks = 0; ks < 16; ++ks) {
#pragma unroll
            for (int j = 0; j < 4; ++j) {
                int rb = j * 16 + fr;
                int ck = (ks * 4 + fq) ^ (rb & 7);
                bf16x8 bf = *(const bf16x8*)&Bt[rb * 512 + ck * 8];
                acc[j] = __builtin_amdgcn_mfma_f32_16x16x32_bf16(af[ks], bf, acc[j], 0, 0, 0);
            }
        }

        // LSTM cell + h stores (critical path).
#pragma unroll
        for (int rr = 0; rr < 4; ++rr) {
            bool mt = (t < LL[rr]);
            float gi = acc[0][rr] + pv[rr][0];
            float gf = acc[1][rr] + pv[rr][1];
            float gg = acc[2][rr] + pv[rr][2];
            float go = acc[3][rr] + pv[rr][3];
            float c2 = sigm(gf) * c_own[rr] + sigm(gi) * tanhfast(gg);
            float h2 = sigm(go) * tanhfast(c2);
            if (!mt) { c2 = c_own[rr]; h2 = h_own[rr]; }
            c_own[rr] = c2;
            h_own[rr] = h2;
            store_h_dev(&hout[sidx[rr]], (bf16_t)h2);
        }
        asm volatile("s_waitcnt vmcnt(0)" ::: "memory");  // h stores device-visible
        __syncthreads();
        if (tid == 0)
            __hip_atomic_fetch_add(&ctr[gslot], 1u, __ATOMIC_RELAXED, __HIP_MEMORY_SCOPE_AGENT);

        // Off-critical-path: output stores + next-step PRE prefetch (overlap poll).
#pragma unroll
        for (int rr = 0; rr < 4; ++rr) {
            bool mt = (t < LL[rr]);
            int trow = (d == 0 || !mt) ? t : (LL[rr] - 1 - t);
            size_t orow = (size_t)trow * M_B + mm[rr];
            if (mode == 0) H1[orow * 1024 + d * H_DIM + u] = (bf16_t)h_own[rr];
            else           OUT[orow * 1024 + d * H_DIM + u] = mt ? h_own[rr] : 0.f;
        }
        float pvn[4][4];
        if (tt + 1 < TC) {
#pragma unroll
            for (int rr = 0; rr < 4; ++rr) {
                const float* prow = pbase[rr] + (size_t)(tt + 1) * ((size_t)M_B * G4);
#pragma unroll
                for (int g = 0; g < 4; ++g)
                    pvn[rr][g] = load_f32_async(prow + g * 16);
            }
        }

        if (tid == 0) {
            unsigned int tgt = (unsigned int)(s_base + tt + 1) * 32u;
            while (__hip_atomic_load(&ctr[gslot], __ATOMIC_RELAXED, __HIP_MEMORY_SCOPE_AGENT) < tgt)
                __builtin_amdgcn_s_sleep(2);
        }
        __syncthreads();

        if (tt + 1 < TC) {
#pragma unroll
            for (int rr = 0; rr < 4; ++rr)
#pragma unroll
                for (int g = 0; g < 4; ++g)
                    pv[rr][g] = pvn[rr][g];
        }
    }

#pragma unroll
    for (int rr = 0; rr < 4; ++rr) cfb[sidx[rr]] = c_own[rr];
}

// ---------------------------------------------------------------------------
extern "C" void kernel_launch(void* const* d_in, const int* in_sizes, int n_in,
                              void* d_out, int out_size, void* d_ws, size_t ws_size,
                              hipStream_t stream)
{
    const int*   F      = (const int*)d_in[0];
    const int*   F_lens = (const int*)d_in[1];
    const float* emb    = (const float*)d_in[2];
    const float* Wih0   = (const float*)d_in[3];
    const float* Whh0   = (const float*)d_in[4];
    const float* b0     = (const float*)d_in[5];
    const float* Wih1   = (const float*)d_in[6];
    const float* Whh1   = (const float*)d_in[7];
    const float* b1     = (const float*)d_in[8];
    float* OUT = (float*)d_out;

    // Base workspace (~155 MiB), 256B-aligned blocks.
    char* p = (char*)d_ws;
    auto alloc = [&](size_t bytes) { char* q = p; p += (bytes + 255) & ~(size_t)255; return (void*)q; };
    bf16_t* X0    = (bf16_t*)alloc((size_t)N_ROWS * E_DIM * 2);   // 64 MiB
    bf16_t* H1    = (bf16_t*)alloc((size_t)N_ROWS * 1024 * 2);    // 64 MiB
    bf16_t* Wih0p = (bf16_t*)alloc((size_t)2 * G4 * E_DIM * 2);   // 8 MiB
    bf16_t* Whh0p = (bf16_t*)alloc((size_t)2 * G4 * H_DIM * 2);   // 4 MiB
    bf16_t* Wih1p = (bf16_t*)alloc((size_t)2 * G4 * E_DIM * 2);   // 8 MiB
    bf16_t* Whh1p = (bf16_t*)alloc((size_t)2 * G4 * H_DIM * 2);   // 4 MiB
    float*  b0p   = (float*)alloc((size_t)2 * G4 * 4);
    float*  b1p   = (float*)alloc((size_t)2 * G4 * 4);
    int*    srcrow= (int*)alloc((size_t)N_ROWS * 4);              // 128 KiB
    bf16_t* hbA   = (bf16_t*)alloc((size_t)2 * M_B * H_DIM * 2);
    bf16_t* hbB   = (bf16_t*)alloc((size_t)2 * M_B * H_DIM * 2);
    float*  cfb   = (float*)alloc((size_t)2 * M_B * H_DIM * 4);
    unsigned int* ctr = (unsigned int*)alloc(512);
    size_t base_used = (size_t)(p - (char*)d_ws);

    // Time-chunk: cap at 32 so the f32 PRE chunk (2*TC*256*2048*4 = 134 MB at
    // TC=32) fits the 256 MiB Infinity Cache -> gemm writes absorbed by L3,
    // lstm reads hit L3, PRE never round-trips HBM.
    int TC = 0;
    const int tcs[6] = {32, 16, 8, 4, 2, 1};
    for (int i = 0; i < 6; ++i) {
        size_t need = base_used + (size_t)2 * tcs[i] * M_B * G4 * 4;
        if (need <= ws_size) { TC = tcs[i]; break; }
    }
    if (TC == 0) return;  // cannot run at all
    float* PREc = (float*)p;
    const int TCR = TC * M_B;

    hipMemsetAsync(ctr, 0, 512, stream);
    permute_all_kernel<<<dim3(2 * 2 * G4), 256, 0, stream>>>(
        Wih0, Whh0, b0, Wih1, Whh1, b1, Wih0p, Whh0p, Wih1p, Whh1p, b0p, b1p);
    embed_kernel<<<dim3(N_ROWS), 256, 0, stream>>>(F, emb, F_lens, X0, srcrow);

    for (int layer = 0; layer < 2; ++layer) {
        const bf16_t* Xin  = layer ? H1 : X0;
        const bf16_t* Wihp = layer ? Wih1p : Wih0p;
        const bf16_t* Whhp = layer ? Whh1p : Whh0p;
        const float*  bp   = layer ? b1p : b0p;

        hipMemsetAsync(hbA, 0, (size_t)2 * M_B * H_DIM * 2, stream);
        hipMemsetAsync(cfb, 0, (size_t)2 * M_B * H_DIM * 4, stream);

        for (int c = 0; c < S_LEN / TC; ++c) {
            gemm_pre_kernel<<<dim3(2 * (TCR / BM) * 16), 256, 0, stream>>>(
                Xin, Wihp, bp, srcrow, PREc, c * TCR, TCR);

            lstm_chunk_kernel<<<dim3(32, 4, 2), dim3(256), 0, stream>>>(
                Whhp, PREc, F_lens, cfb, hbA, hbB, H1, OUT, ctr,
                c * TC, TC, TCR, layer, layer * S_LEN + c * TC);
        }
    }
}